// Round 14
// baseline (688.937 us; speedup 1.0000x reference)
//
#include <hip/hip_runtime.h>
#include <cstddef>

typedef _Float16 f16;
typedef f16 f16x4 __attribute__((ext_vector_type(4)));
typedef f16 f16x8 __attribute__((ext_vector_type(8)));
typedef float f32x4 __attribute__((ext_vector_type(4)));
typedef float f32x16 __attribute__((ext_vector_type(16)));

// async global->LDS, 16B per lane. LDS dest = uniform base + lane*16 (HW);
// global src is per-lane.
__device__ inline void gld_lds16(const f16* g, f16* l) {
    __builtin_amdgcn_global_load_lds(
        (const __attribute__((address_space(1))) void*)g,
        (__attribute__((address_space(3))) void*)l, 16, 0, 0);
}

// ---------------------------------------------------------------------------
// 16x16x32 MFMA submanifold conv, A-direct / B-in-LDS (R13-proven).
// Used for conv1 (sbuf), conv3 + head (whole-B). See conv_mfma32 for conv2.
// ---------------------------------------------------------------------------
template<int C, int NTB, int CS, int WCO, int TERMS, int WAVES, int BMODE,
         int OUTM, int PIPEA, int MROW>
__global__ __launch_bounds__(WAVES * 64)
void conv_mfma(const f16* __restrict__ fin, size_t in_plane,
               const int* __restrict__ nbr,
               const f16* __restrict__ Wb,
               void* __restrict__ outv, int ostride, int ooff, size_t out_plane,
               int CO_real, int N, int Nstore, int tilesPad)
{
    constexpr int KK   = C / 32;
    constexpr int KKL  = (TERMS == 2) ? KK : 1;
    constexpr int NTBT = WCO * NTB;
    constexpr int CH   = KK * NTBT * TERMS;
    constexpr int WROW = WAVES / WCO;
    constexpr int ROWS = WROW * MROW * 16;
    constexpr int BUFS = (BMODE == 0) ? 27 : ((BMODE == 1) ? 2 : 1);
    static_assert(!(BMODE == 0 && MROW != 1), "BMODE0 path is MROW=1");
    __shared__ f16 sB[BUFS * CH * 512];

    const int lane = threadIdx.x & 63;
    const int w    = threadIdx.x >> 6;
    const int wco  = w % WCO;
    const int wrow = w / WCO;
    int gid = blockIdx.x;
    { const int q = (tilesPad * CS) >> 3; gid = (gid & 7) * q + (gid >> 3); }
    const int tile = gid / CS;
    const int cs   = gid - tile * CS;
    const int n0   = tile * ROWS;
    const int NZ   = N;                          // zero row
    const int h8   = (lane >> 4) * 8;

    int  site[MROW];
    bool sv[MROW];
#pragma unroll
    for (int r = 0; r < MROW; ++r) {
        site[r] = n0 + (wrow * MROW + r) * 16 + (lane & 15);
        sv[r]   = site[r] < N;
    }

    auto nbrIdx = [&](int r, int k) -> int {
        int v = sv[r] ? nbr[(size_t)site[r] * 27 + k] : -1;
        return (v < 0) ? NZ : v;
    };

    auto stageK = [&](int k, int buf) {
        const f16* src = Wb + ((size_t)(k * CS + cs) * CH) * 512 + lane * 8;
        f16* dst = &sB[(size_t)buf * CH * 512];
#pragma unroll
        for (int c = w; c < CH; c += WAVES)
            gld_lds16(src + (size_t)c * 512, dst + (size_t)c * 512);
    };

    f32x4 acc[MROW * NTB], acc2[MROW * NTB];
#pragma unroll
    for (int i = 0; i < MROW * NTB; ++i) {
        acc[i]  = (f32x4){0.f, 0.f, 0.f, 0.f};
        acc2[i] = (f32x4){0.f, 0.f, 0.f, 0.f};
    }

    f16x8 va[MROW * KK], vl[MROW * KKL];
    f16x8 vaB[(BMODE == 0 && PIPEA) ? KK : 1], vlB[(BMODE == 0 && PIPEA) ? KKL : 1];

    auto loadA = [&](int idx, f16x8* pva, f16x8* pvl) {
        const f16* arow = fin + (size_t)idx * C + h8;
#pragma unroll
        for (int kk = 0; kk < KK; ++kk) {
            pva[kk] = *(const f16x8*)(arow + kk * 32);
            if constexpr (TERMS == 2)
                pvl[kk] = *(const f16x8*)(arow + in_plane + kk * 32);
        }
    };

    auto mfmaPhase = [&](const f16x8* pva, const f16x8* pvl, int kbuf) {
        const f16* sBc = &sB[(size_t)kbuf * CH * 512] + lane * 8;
#pragma unroll
        for (int kk = 0; kk < KK; ++kk) {
#pragma unroll
            for (int nt = 0; nt < NTB; ++nt) {
                const f16* bp = sBc + (size_t)((kk * NTBT + wco * NTB + nt) * TERMS) * 512;
                const f16x8 bh = *(const f16x8*)bp;
                if constexpr (TERMS == 2) {
                    const f16x8 bl = *(const f16x8*)(bp + 512);
#pragma unroll
                    for (int r = 0; r < MROW; ++r) {
                        acc[r * NTB + nt]  = __builtin_amdgcn_mfma_f32_16x16x32_f16(
                            pva[r * KK + kk], bh, acc[r * NTB + nt], 0, 0, 0);
                        acc2[r * NTB + nt] = __builtin_amdgcn_mfma_f32_16x16x32_f16(
                            pva[r * KK + kk], bl, acc2[r * NTB + nt], 0, 0, 0);
                        acc2[r * NTB + nt] = __builtin_amdgcn_mfma_f32_16x16x32_f16(
                            pvl[r * KK + kk], bh, acc2[r * NTB + nt], 0, 0, 0);
                    }
                } else {
#pragma unroll
                    for (int r = 0; r < MROW; ++r)
                        acc[r * NTB + nt] = __builtin_amdgcn_mfma_f32_16x16x32_f16(
                            pva[r * KK + kk], bh, acc[r * NTB + nt], 0, 0, 0);
                }
            }
        }
    };

    if constexpr (BMODE == 1) {
        int idxN[MROW];
#pragma unroll
        for (int r = 0; r < MROW; ++r)
            loadA(nbrIdx(r, 0), &va[r * KK], &vl[r * KKL]);
        stageK(0, 0);
#pragma unroll
        for (int r = 0; r < MROW; ++r) idxN[r] = nbrIdx(r, 1);
        __syncthreads();

        for (int k = 0; k < 27; ++k) {
            if (k + 1 < 27) stageK(k + 1, (k + 1) & 1);
            mfmaPhase(va, vl, k & 1);
            if (k + 1 < 27) {
#pragma unroll
                for (int r = 0; r < MROW; ++r)
                    loadA(idxN[r], &va[r * KK], &vl[r * KKL]);
#pragma unroll
                for (int r = 0; r < MROW; ++r)
                    idxN[r] = (k + 2 < 27) ? nbrIdx(r, k + 2) : NZ;
                __syncthreads();
            }
        }
    } else if constexpr (BMODE == 2) {
        int idxN[MROW];
#pragma unroll
        for (int r = 0; r < MROW; ++r)
            loadA(nbrIdx(r, 0), &va[r * KK], &vl[r * KKL]);
#pragma unroll
        for (int r = 0; r < MROW; ++r) idxN[r] = nbrIdx(r, 1);

        for (int k = 0; k < 27; ++k) {
            stageK(k, 0);
            __syncthreads();
            mfmaPhase(va, vl, 0);
            if (k + 1 < 27) {
#pragma unroll
                for (int r = 0; r < MROW; ++r)
                    loadA(idxN[r], &va[r * KK], &vl[r * KKL]);
#pragma unroll
                for (int r = 0; r < MROW; ++r)
                    idxN[r] = (k + 2 < 27) ? nbrIdx(r, k + 2) : NZ;
                __syncthreads();
            }
        }
    } else {
#pragma unroll
        for (int c = w; c < 27 * CH; c += WAVES)
            gld_lds16(Wb + (size_t)c * 512 + lane * 8, &sB[(size_t)c * 512]);
        int idxC = nbrIdx(0, 0);
        loadA(idxC, va, vl);
        int idxN = nbrIdx(0, 1);
        __syncthreads();

        if constexpr (PIPEA) {
            auto body = [&](int k, f16x8* vac, f16x8* vlc, f16x8* van, f16x8* vln) {
                if (k >= 27) return;
                if (k + 1 < 27) {
                    loadA(idxN, van, vln);
                    idxN = (k + 2 < 27) ? nbrIdx(0, k + 2) : NZ;
                }
                mfmaPhase(vac, vlc, k);
            };
            for (int k2 = 0; k2 < 27; k2 += 2) {
                body(k2, va, vl, vaB, vlB);
                body(k2 + 1, vaB, vlB, va, vl);
            }
        } else {
            for (int k = 0; k < 27; ++k) {
                mfmaPhase(va, vl, k);
                if (k + 1 < 27) {
                    loadA(idxN, va, vl);
                    idxN = (k + 2 < 27) ? nbrIdx(0, k + 2) : NZ;
                }
            }
        }
    }

    const int colg = lane & 15;
    const int rg   = lane >> 4;
#pragma unroll
    for (int r = 0; r < MROW; ++r) {
#pragma unroll
        for (int nt = 0; nt < NTB; ++nt) {
#pragma unroll
            for (int j = 0; j < 4; ++j) {
                float v = acc[r * NTB + nt][j];
                if constexpr (TERMS == 2) v += acc2[r * NTB + nt][j] * (1.f / 4096.f);
                const int n  = n0 + (wrow * MROW + r) * 16 + rg * 4 + j;
                const int co = ((cs * WCO + wco) * NTB + nt) * 16 + colg;
                if (n < Nstore && co < CO_real) {
                    if constexpr (OUTM == 0) {
                        ((float*)outv)[(size_t)n * ostride + ooff + co] = v;
                    } else if constexpr (OUTM == 1) {
                        ((f16*)outv)[(size_t)n * ostride + co] = (f16)v;
                    } else {
                        f16* o = (f16*)outv;
                        const f16 h = (f16)v;
                        o[(size_t)n * ostride + co] = h;
                        o[out_plane + (size_t)n * ostride + co] = (f16)((v - (float)h) * 4096.f);
                    }
                }
            }
        }
    }
}

// ---------------------------------------------------------------------------
// 32x32x16 MFMA conv (conv2): one 32x32 MFMA consumes the same 1KB B
// fragment as a 16x16x32 but does 2x the FLOPs -> B-LDS-read traffic halves
// (R13 diagnosis: conv2 is LDS-read-BW bound, 185us of 212us). Wave owns 32
// sites; NTB=1 (CO = CS x 32 cols); A-gather x1.5 vs CS=2 is cheap after the
// mask remap (15.7MB FETCH).
// Fragment maps: A row=lane&31, k=(lane>>5)*8+j; B col=lane&31, same k;
// D col=lane&31, row=(reg&3)+8*(reg>>2)+4*(lane>>5)  [guide, HW-verified].
// Structure (stage/barrier/pipeline) identical to conv_mfma BMODE=1.
// ---------------------------------------------------------------------------
template<int C, int CS, int WAVES>
__global__ __launch_bounds__(WAVES * 64)
void conv_mfma32(const f16* __restrict__ fin, size_t in_plane,
                 const int* __restrict__ nbr,
                 const f16* __restrict__ Wb,   // [(k*CS+cs)*KT+kt][term] chunks
                 f16* __restrict__ outv, int ostride, size_t out_plane,
                 int N, int Nstore, int tilesPad)
{
    constexpr int KT   = C / 16;                 // k-tiles of 16
    constexpr int CH   = KT * 2;                 // chunks per (k, cs), TERMS=2
    constexpr int ROWS = WAVES * 32;
    __shared__ f16 sB[2 * CH * 512];

    const int lane = threadIdx.x & 63;
    const int w    = threadIdx.x >> 6;
    int gid = blockIdx.x;
    { const int q = (tilesPad * CS) >> 3; gid = (gid & 7) * q + (gid >> 3); }
    const int tile = gid / CS;
    const int cs   = gid - tile * CS;
    const int n0   = tile * ROWS;
    const int NZ   = N;
    const int h8   = (lane >> 5) * 8;

    const int site = n0 + w * 32 + (lane & 31);
    const bool sv  = site < N;

    auto nbrIdx = [&](int k) -> int {
        int v = sv ? nbr[(size_t)site * 27 + k] : -1;
        return (v < 0) ? NZ : v;
    };

    auto stageK = [&](int k, int buf) {
        const f16* src = Wb + ((size_t)(k * CS + cs) * CH) * 512 + lane * 8;
        f16* dst = &sB[(size_t)buf * CH * 512];
#pragma unroll
        for (int c = w; c < CH; c += WAVES)
            gld_lds16(src + (size_t)c * 512, dst + (size_t)c * 512);
    };

    f32x16 acc = {}, acc2 = {};
    f16x8 va[KT], vl[KT];

    auto loadA = [&](int idx) {
        const f16* arow = fin + (size_t)idx * C + h8;
#pragma unroll
        for (int kt = 0; kt < KT; ++kt) {
            va[kt] = *(const f16x8*)(arow + kt * 16);
            vl[kt] = *(const f16x8*)(arow + in_plane + kt * 16);
        }
    };

    auto mfmaPhase = [&](int kbuf) {
        const f16* sBc = &sB[(size_t)kbuf * CH * 512] + lane * 8;
#pragma unroll
        for (int kt = 0; kt < KT; ++kt) {
            const f16* bp = sBc + (size_t)(kt * 2) * 512;
            const f16x8 bh = *(const f16x8*)bp;
            const f16x8 bl = *(const f16x8*)(bp + 512);
            acc  = __builtin_amdgcn_mfma_f32_32x32x16_f16(va[kt], bh, acc, 0, 0, 0);
            acc2 = __builtin_amdgcn_mfma_f32_32x32x16_f16(va[kt], bl, acc2, 0, 0, 0);
            acc2 = __builtin_amdgcn_mfma_f32_32x32x16_f16(vl[kt], bh, acc2, 0, 0, 0);
        }
    };

    // prologue (R13-proven order): A(0) first, stage B(0), prefetch idx(1)
    loadA(nbrIdx(0));
    stageK(0, 0);
    int idxN = nbrIdx(1);
    __syncthreads();

    for (int k = 0; k < 27; ++k) {
        if (k + 1 < 27) stageK(k + 1, (k + 1) & 1);
        mfmaPhase(k & 1);
        if (k + 1 < 27) {
            loadA(idxN);
            idxN = (k + 2 < 27) ? nbrIdx(k + 2) : NZ;
            __syncthreads();
        }
    }

    // D: col=lane&31, row=(r&3)+8*(r>>2)+4*(lane>>5)
    const int colg = cs * 32 + (lane & 31);
    const int rbase = n0 + w * 32 + 4 * (lane >> 5);
#pragma unroll
    for (int r = 0; r < 16; ++r) {
        const int n = rbase + (r & 3) + 8 * (r >> 2);
        if (n < Nstore) {
            const float v = acc[r] + acc2[r] * (1.f / 4096.f);
            const f16 h = (f16)v;
            outv[(size_t)n * ostride + colg] = h;
            outv[out_plane + (size_t)n * ostride + colg] = (f16)((v - (float)h) * 4096.f);
        }
    }
}

// nbrm[i] = nbr[i] if that neighbor survives the attention mask, else -1.
__global__ __launch_bounds__(256)
void remap_nbr(const int* __restrict__ nbr, const float* __restrict__ att,
               int* __restrict__ nbrm, size_t total)
{
    const size_t i = (size_t)blockIdx.x * 256 + threadIdx.x;
    if (i >= total) return;
    const int j = nbr[i];
    nbrm[i] = (j >= 0 && att[j] > 0.5f) ? j : -1;
}

// ---------------------------------------------------------------------------
// P-factorized score: P[k][R][c] = f[R] @ Ws[k][:,c] as ONE dense GEMM
// f[N x C] @ Wflat[C x 54->64] (no gather). P is f32 [27][N][2].
// ---------------------------------------------------------------------------
template<int C>
__global__ __launch_bounds__(256)
void pgemm_score(const f16* __restrict__ fin, size_t plane,
                 const f16* __restrict__ Wb,   // (C/32)*4*2 chunks
                 float* __restrict__ P, int N)
{
    constexpr int KK = C / 32;
    constexpr int CH = KK * 4 * 2;
    __shared__ f16 sB[CH * 512];

    const int tid  = threadIdx.x;
    const int lane = tid & 63;
    const int w    = tid >> 6;

    const int n0 = blockIdx.x * 64;
    int site = n0 + w * 16 + (lane & 15);
    if (site > N) site = N;                 // zero row for tails
    const int h8 = (lane >> 4) * 8;

    f16x8 va[KK], vl[KK];
    const f16* arow = fin + (size_t)site * C + h8;
#pragma unroll
    for (int kk = 0; kk < KK; ++kk) {
        va[kk] = *(const f16x8*)(arow + kk * 32);
        vl[kk] = *(const f16x8*)(arow + plane + kk * 32);
    }
    for (int c = w; c < CH; c += 4)
        gld_lds16(Wb + (size_t)c * 512 + lane * 8, &sB[(size_t)c * 512]);

    f32x4 acc[4], acc2[4];
#pragma unroll
    for (int nt = 0; nt < 4; ++nt) {
        acc[nt]  = (f32x4){0.f, 0.f, 0.f, 0.f};
        acc2[nt] = (f32x4){0.f, 0.f, 0.f, 0.f};
    }
    __syncthreads();

#pragma unroll
    for (int kk = 0; kk < KK; ++kk) {
#pragma unroll
        for (int nt = 0; nt < 4; ++nt) {
            const f16* bp = &sB[(size_t)((kk * 4 + nt) * 2) * 512] + lane * 8;
            const f16x8 bh = *(const f16x8*)bp;
            const f16x8 bl = *(const f16x8*)(bp + 512);
            acc[nt]  = __builtin_amdgcn_mfma_f32_16x16x32_f16(va[kk], bh, acc[nt], 0, 0, 0);
            acc2[nt] = __builtin_amdgcn_mfma_f32_16x16x32_f16(va[kk], bl, acc2[nt], 0, 0, 0);
            acc2[nt] = __builtin_amdgcn_mfma_f32_16x16x32_f16(vl[kk], bh, acc2[nt], 0, 0, 0);
        }
    }

    const int colg = lane & 15;
    const int rg   = lane >> 4;
#pragma unroll
    for (int nt = 0; nt < 4; ++nt) {
#pragma unroll
        for (int j = 0; j < 4; ++j) {
            const float r = acc[nt][j] + acc2[nt][j] * (1.f / 4096.f);
            const int n  = n0 + w * 16 + rg * 4 + j;
            const int co = nt * 16 + colg;
            if (n < N && co < 54)
                P[(size_t)(co >> 1) * N * 2 + (size_t)n * 2 + (co & 1)] = r;
        }
    }
}

// score(S) = sum_k P[k][nbr(S,k)]  (f32, k-ordered like the reference);
// also fills the coords columns of ppn.
__global__ __launch_bounds__(256)
void reduce_score(const float* __restrict__ P, const int* __restrict__ nbr,
                  const int* __restrict__ coords, float* __restrict__ ppn, int N)
{
    const int site = blockIdx.x * 256 + threadIdx.x;
    if (site >= N) return;
    float s0 = 0.f, s1 = 0.f;
    const size_t pl = (size_t)N * 2;
#pragma unroll
    for (int k = 0; k < 27; ++k) {
        const int idx = nbr[(size_t)site * 27 + k];
        if (idx >= 0) {
            const float2 p = *(const float2*)(P + (size_t)k * pl + (size_t)idx * 2);
            s0 += p.x; s1 += p.y;
        }
    }
    float* row = ppn + (size_t)site * 6;
    const int* cr = coords + (size_t)site * 4;
    row[0] = (float)cr[0]; row[1] = (float)cr[1];
    row[2] = (float)cr[2]; row[3] = (float)cr[3];
    row[4] = s0; row[5] = s1;
}

// ---------------------------------------------------------------------------
// Pre-pass: f32 rows (optionally x att-mask) -> f16 split planes, plus a
// zero row at index N (gather target for missing neighbors / tail sites).
// ---------------------------------------------------------------------------
template<int TERMS>
__global__ __launch_bounds__(256)
void prepass(const float* __restrict__ f, const float* __restrict__ att,
             f16* __restrict__ dst, size_t plane, int C4, int N)
{
    const size_t i = (size_t)blockIdx.x * 256 + threadIdx.x;
    const size_t total = (size_t)(N + 1) * C4;
    if (i >= total) return;
    const int row = (int)(i / C4);
    float4 v = make_float4(0.f, 0.f, 0.f, 0.f);
    if (row < N) {
        v = *(const float4*)(f + i * 4);
        if (att != nullptr) {
            const float a = att[row];
            v.x *= a; v.y *= a; v.z *= a; v.w *= a;
        }
    }
    const float xs[4] = {v.x, v.y, v.z, v.w};
    f16x4 hi, lo;
#pragma unroll
    for (int j = 0; j < 4; ++j) {
        const f16 h = (f16)xs[j];
        hi[j] = h;
        lo[j] = (f16)((xs[j] - (float)h) * 4096.f);
    }
    *(f16x4*)(dst + i * 4) = hi;
    if constexpr (TERMS == 2)
        *(f16x4*)(dst + plane + i * 4) = lo;
}

// Pack fp32 W[27][C][CO_real] into 16x16 fragment chunks:
// chunk id = ((((k*CS + cs)*KK + kk)*NTB + nt)*TERMS + term), 512 f16 each.
__global__ __launch_bounds__(256)
void pack_w_f16(const float* __restrict__ W, f16* __restrict__ Wb,
                int C, int CO_real, int CS, int NTB, int TERMS)
{
    const int KK = C / 32;
    const int total = 27 * CS * KK * NTB * TERMS * 64;
    const int t = blockIdx.x * blockDim.x + threadIdx.x;
    if (t >= total) return;
    const int lane = t & 63;
    int cid = t >> 6;
    const int term = cid % TERMS; cid /= TERMS;
    const int nt   = cid % NTB;   cid /= NTB;
    const int kk   = cid % KK;    cid /= KK;
    const int cs   = cid % CS;
    const int k    = cid / CS;
    const int co   = (cs * NTB + nt) * 16 + (lane & 15);
#pragma unroll
    for (int j = 0; j < 8; ++j) {
        const int ci = kk * 32 + (lane >> 4) * 8 + j;
        const float x = (co < CO_real) ? W[((size_t)k * C + ci) * CO_real + co] : 0.f;
        const f16 h = (f16)x;
        Wb[(size_t)t * 8 + j] = (term == 0) ? h : (f16)((x - (float)h) * 4096.f);
    }
}

// Pack fp32 W[27][C][CO] into 32x32 fragment chunks:
// chunk id = (((k*CS + cs)*KT + kt)*2 + term); within chunk lane l, elem j:
// ci = kt*16 + (l>>5)*8 + j, co = cs*32 + (l&31).
__global__ __launch_bounds__(256)
void pack_w32(const float* __restrict__ W, f16* __restrict__ Wb,
              int C, int CO, int CS)
{
    const int KT = C / 16;
    const int total = 27 * CS * KT * 2 * 64;
    const int t = blockIdx.x * blockDim.x + threadIdx.x;
    if (t >= total) return;
    const int lane = t & 63;
    int cid = t >> 6;
    const int term = cid % 2;  cid >>= 1;
    const int kt   = cid % KT; cid /= KT;
    const int cs   = cid % CS;
    const int k    = cid / CS;
    const int co   = cs * 32 + (lane & 31);
#pragma unroll
    for (int j = 0; j < 8; ++j) {
        const int ci = kt * 16 + (lane >> 5) * 8 + j;
        const float x = (co < CO) ? W[((size_t)k * C + ci) * CO + co] : 0.f;
        const f16 h = (f16)x;
        Wb[(size_t)t * 8 + j] = (term == 0) ? h : (f16)((x - (float)h) * 4096.f);
    }
}

// Pack score weights [27][C][2] as a flat [C x 54->64] fragment set,
// chunk id = ((kk*4 + nt)*2 + term); flat col co = 2k + c.
__global__ __launch_bounds__(256)
void pack_ws_flat(const float* __restrict__ W, f16* __restrict__ Wb, int C)
{
    const int KK = C / 32;
    const int total = KK * 4 * 2 * 64;
    const int t = blockIdx.x * blockDim.x + threadIdx.x;
    if (t >= total) return;
    const int lane = t & 63;
    int cid = t >> 6;
    const int term = cid % 2;
    const int nt   = (cid >> 1) % 4;
    const int kk   = cid >> 3;
    const int co   = nt * 16 + (lane & 15);
#pragma unroll
    for (int j = 0; j < 8; ++j) {
        const int ci = kk * 32 + (lane >> 4) * 8 + j;
        const float x = (co < 54) ? W[((size_t)(co >> 1) * C + ci) * 2 + (co & 1)] : 0.f;
        const f16 h = (f16)x;
        Wb[(size_t)t * 8 + j] = (term == 0) ? h : (f16)((x - (float)h) * 4096.f);
    }
}

// Pack the fused head [27][32][{3|2|5}->10] directly into fragment chunks
// (chunk per k; single term).
__global__ __launch_bounds__(256)
void pack_wh_frag(const float* __restrict__ wp, const float* __restrict__ ws,
                  const float* __restrict__ wt, f16* __restrict__ Wb)
{
    const int t = blockIdx.x * blockDim.x + threadIdx.x;
    if (t >= 27 * 64) return;
    const int lane = t & 63;
    const int k    = t >> 6;
    const int co   = lane & 15;
#pragma unroll
    for (int j = 0; j < 8; ++j) {
        const int ci = (lane >> 4) * 8 + j;
        float x = 0.f;
        if (co < 3)       x = wp[((size_t)k * 32 + ci) * 3 + co];
        else if (co < 5)  x = ws[((size_t)k * 32 + ci) * 2 + (co - 3)];
        else if (co < 10) x = wt[((size_t)k * 32 + ci) * 5 + (co - 5)];
        Wb[(size_t)t * 8 + j] = (f16)x;
    }
}

__global__ __launch_bounds__(256)
void att_kernel(const float* __restrict__ ppn, const int* __restrict__ parent,
                float* __restrict__ att, int N)
{
    const int i = blockIdx.x * blockDim.x + threadIdx.x;
    if (i >= N) return;
    const int p = parent[i];
    const float s0 = ppn[(size_t)p * 6 + 4];
    const float s1 = ppn[(size_t)p * 6 + 5];
    const float m  = fmaxf(s0, s1);
    const float e0 = expf(s0 - m);
    const float e1 = expf(s1 - m);
    const float p1 = e1 / (e0 + e1);
    att[i] = (p1 > 0.8f) ? 1.f : 0.f;
}

extern "C" void kernel_launch(void* const* d_in, const int* in_sizes, int n_in,
                              void* d_out, int out_size, void* d_ws, size_t ws_size,
                              hipStream_t stream)
{
    const float* f1       = (const float*)d_in[0];
    const float* f2       = (const float*)d_in[1];
    const float* f3       = (const float*)d_in[2];
    const float* w1_conv  = (const float*)d_in[3];
    const float* w1_score = (const float*)d_in[4];
    const float* w2_conv  = (const float*)d_in[5];
    const float* w2_score = (const float*)d_in[6];
    const float* w3_conv  = (const float*)d_in[7];
    const float* w3_pix   = (const float*)d_in[8];
    const float* w3_score = (const float*)d_in[9];
    const float* w3_type  = (const float*)d_in[10];
    const int* coords1    = (const int*)d_in[11];
    const int* coords2    = (const int*)d_in[12];
    const int* nbr1       = (const int*)d_in[13];
    const int* nbr2       = (const int*)d_in[14];
    const int* nbr3       = (const int*)d_in[15];
    const int* parent12   = (const int*)d_in[16];
    const int* parent23   = (const int*)d_in[17];

    const int N1 = in_sizes[0] / 160;   // 20000
    const int N2 = in_sizes[1] / 96;    // 160000
    const int N3 = in_sizes[2] / 32;    // 320000

    // Output layout: points[N3,10] | ppn1[N1,6] | ppn2[N2,6] | att[N2] | att2[N3]
    float* points = (float*)d_out;
    float* ppn1   = points + (size_t)N3 * 10;
    float* ppn2   = ppn1 + (size_t)N1 * 6;
    float* attn   = ppn2 + (size_t)N2 * 6;
    float* attn2  = attn + (size_t)N2;

    // Workspace (all conv inputs have N+1 rows; row N = zeros).
    const size_t p1 = (size_t)(N1 + 1) * 160;
    const size_t p2 = (size_t)(N2 + 1) * 96;
    const size_t p3 = (size_t)(N3 + 1) * 32;
    f16* f1s  = (f16*)d_ws;           // 2*p1 = 12.8MB
    f16* xs   = f1s + 2 * p1;         // 2*p1
    f16* f2s  = xs + 2 * p1;          // 2*p2 = 61.4MB
    f16* ys   = f2s + 2 * p2;         // 2*p2
    float* P1 = (float*)f1s;          // 4.3MB  (dead after reduce1)
    int* nbr2m = (int*)f1s;           // 17.3MB <= 25.6MB (f1s+xs)
    f16* f3s  = f1s;                  // 20.5MB (after conv2)
    float* P2 = (float*)f2s;          // 34.6MB (dead after reduce2)
    f16* zs   = f2s;                  // 20.5MB
    int* nbr3m = (int*)((char*)f2s + ((p3 * 2 + 255) & ~(size_t)255));
    f16* Wb1  = ys + 2 * p2;                // 2700 chunks (conv1 16x16)
    f16* Wb2  = Wb1 + (size_t)2700 * 512;   // conv2 32x32: 27*3cs*6kt*2 = 972
    f16* Wb3  = Wb2 + (size_t)972 * 512;    // 54
    f16* Wbh  = Wb3 + (size_t)54 * 512;     // 27
    f16* Wsf1 = Wbh + (size_t)27 * 512;     // 40 (score1 flat)
    f16* Wsf2 = Wsf1 + (size_t)40 * 512;    // 24 (score2 flat)

    // ---- weight packing ----
    pack_w_f16<<<(2700 * 64 + 255) / 256, 256, 0, stream>>>(w1_conv, Wb1, 160, 160, 2, 5, 2);
    pack_w32<<<(972 * 64 + 255) / 256, 256, 0, stream>>>(w2_conv, Wb2, 96, 96, 3);
    pack_w_f16<<<(54 * 64 + 255) / 256, 256, 0, stream>>>(w3_conv, Wb3, 32, 32, 1, 2, 1);
    pack_wh_frag<<<(27 * 64 + 255) / 256, 256, 0, stream>>>(w3_pix, w3_score, w3_type, Wbh);
    pack_ws_flat<<<(40 * 64 + 255) / 256, 256, 0, stream>>>(w1_score, Wsf1, 160);
    pack_ws_flat<<<(24 * 64 + 255) / 256, 256, 0, stream>>>(w2_score, Wsf2, 96);

    // ---- level 1 ----
    prepass<2><<<(int)(((size_t)(N1 + 1) * 40 + 255) / 256), 256, 0, stream>>>(
        f1, nullptr, f1s, p1, 40, N1);
    // conv1: C=160 NTB=5 CS=2 WCO=1 MROW=1, sbuf (50KB LDS, 2 barriers/k).
    conv_mfma<160, 5, 2, 1, 2, 8, 2, 2, 0, 1><<<160 * 2, 512, 0, stream>>>(
        f1s, p1, nbr1, Wb1, xs, 160, 0, p1, 160, N1, N1 + 1, 160);
    pgemm_score<160><<<(N1 + 63) / 64, 256, 0, stream>>>(xs, p1, Wsf1, P1, N1);
    reduce_score<<<(N1 + 255) / 256, 256, 0, stream>>>(P1, nbr1, coords1, ppn1, N1);
    att_kernel<<<(N2 + 255) / 256, 256, 0, stream>>>(ppn1, parent12, attn, N2);

    // ---- level 2 ----
    remap_nbr<<<(int)(((size_t)N2 * 27 + 255) / 256), 256, 0, stream>>>(
        nbr2, attn, nbr2m, (size_t)N2 * 27);
    prepass<2><<<(int)(((size_t)(N2 + 1) * 24 + 255) / 256), 256, 0, stream>>>(
        f2, attn, f2s, p2, 24, N2);
    // conv2: 32x32x16 MFMA, CS=3, WAVES=8, 24KB dbuf, masked-gather remap.
    // ROWS=256, tiles=625 exactly -> pad 632, nwg=1896 (%8==0).
    conv_mfma32<96, 3, 8><<<632 * 3, 512, 0, stream>>>(
        f2s, p2, nbr2m, Wb2, ys, 96, p2, N2, N2 + 1, 632);
    pgemm_score<96><<<(N2 + 63) / 64, 256, 0, stream>>>(ys, p2, Wsf2, P2, N2);
    reduce_score<<<(N2 + 255) / 256, 256, 0, stream>>>(P2, nbr2, coords2, ppn2, N2);
    att_kernel<<<(N3 + 255) / 256, 256, 0, stream>>>(ppn2, parent23, attn2, N3);

    // ---- level 3 (points chain, single-term f16) ----
    remap_nbr<<<(int)(((size_t)N3 * 27 + 255) / 256), 256, 0, stream>>>(
        nbr3, attn2, nbr3m, (size_t)N3 * 27);
    prepass<1><<<(int)(((size_t)(N3 + 1) * 8 + 255) / 256), 256, 0, stream>>>(
        f3, attn2, f3s, 0, 8, N3);
    // conv3: C=32 NTB=2 whole-B (54KB), no k-loop barriers, PIPEA; masked.
    conv_mfma<32, 2, 1, 1, 1, 8, 0, 1, 1, 1><<<2504, 512, 0, stream>>>(
        f3s, 0, nbr3m, Wb3, zs, 32, 0, 0, 32, N3, N3 + 1, 2504);
    // head: C=32 NTB=1 whole-B (27KB), PIPEA. zs is NOT masked -> nbr3.
    conv_mfma<32, 1, 1, 1, 1, 8, 0, 0, 1, 1><<<2504, 512, 0, stream>>>(
        zs, 0, nbr3, Wbh, points, 10, 0, 0, 10, N3, N3, 2504);
}

// Round 15
// 627.478 us; speedup vs baseline: 1.0979x; 1.0979x over previous
//
#include <hip/hip_runtime.h>
#include <cstddef>

typedef _Float16 f16;
typedef f16 f16x4 __attribute__((ext_vector_type(4)));
typedef f16 f16x8 __attribute__((ext_vector_type(8)));
typedef float f32x4 __attribute__((ext_vector_type(4)));

// async global->LDS, 16B per lane. LDS dest = uniform base + lane*16 (HW);
// global src is per-lane.
__device__ inline void gld_lds16(const f16* g, f16* l) {
    __builtin_amdgcn_global_load_lds(
        (const __attribute__((address_space(1))) void*)g,
        (__attribute__((address_space(3))) void*)l, 16, 0, 0);
}

// ---------------------------------------------------------------------------
// 16x16x32 MFMA submanifold conv, A-direct / B-in-LDS.
//  - GEOMETRY (R5..R14 measured): conv2 best = NTB=3 CS=2 MROW=1 WAVES=8,
//    36KB dbuf, 6 independent acc chains (R14's 32x32 variant lost: 2 chains
//    x long latency). conv1 best = sbuf BMODE=2. conv3/head = whole-B BMODE=0.
//  - MASK REMAP (R13, proven): att zeroes ~84% of f2/f3 rows exactly; nbr
//    remapped so masked gathers hit the L1-resident zero row. conv2 FETCH
//    71.7 -> 15.7MB, 261 -> 212us.
//  - MROW in BMODE=0 (R15): per-k MFMA work is tiny (1-2 MFMAs) vs ~200-400
//    cyc gather latency; MROW=4 gives each lane 4-8 independent gathers in
//    flight (MLP), the only lever left for the latency-bound level-3 convs.
//  - TERMS=2: Markidis f16 split (hi + lo*2^12), 3 MFMAs/pair -> ~fp32
//    accuracy (mask-threshold chain). TERMS=1: plain f16 (points chain).
//  - Bijective XCD-chunk swizzle (nwg % 8 == 0).
// ---------------------------------------------------------------------------
template<int C, int NTB, int CS, int WCO, int TERMS, int WAVES, int BMODE,
         int OUTM, int PIPEA, int MROW>
__global__ __launch_bounds__(WAVES * 64)
void conv_mfma(const f16* __restrict__ fin, size_t in_plane,
               const int* __restrict__ nbr,
               const f16* __restrict__ Wb,
               void* __restrict__ outv, int ostride, int ooff, size_t out_plane,
               int CO_real, int N, int Nstore, int tilesPad)
{
    constexpr int KK   = C / 32;
    constexpr int KKL  = (TERMS == 2) ? KK : 1;
    constexpr int NTBT = WCO * NTB;
    constexpr int CH   = KK * NTBT * TERMS;
    constexpr int WROW = WAVES / WCO;
    constexpr int ROWS = WROW * MROW * 16;
    constexpr int BUFS = (BMODE == 0) ? 27 : ((BMODE == 1) ? 2 : 1);
    __shared__ f16 sB[BUFS * CH * 512];

    const int lane = threadIdx.x & 63;
    const int w    = threadIdx.x >> 6;
    const int wco  = w % WCO;
    const int wrow = w / WCO;
    int gid = blockIdx.x;
    { const int q = (tilesPad * CS) >> 3; gid = (gid & 7) * q + (gid >> 3); }
    const int tile = gid / CS;
    const int cs   = gid - tile * CS;
    const int n0   = tile * ROWS;
    const int NZ   = N;                          // zero row
    const int h8   = (lane >> 4) * 8;

    int  site[MROW];
    bool sv[MROW];
#pragma unroll
    for (int r = 0; r < MROW; ++r) {
        site[r] = n0 + (wrow * MROW + r) * 16 + (lane & 15);
        sv[r]   = site[r] < N;
    }

    auto nbrIdx = [&](int r, int k) -> int {
        int v = sv[r] ? nbr[(size_t)site[r] * 27 + k] : -1;
        return (v < 0) ? NZ : v;
    };

    auto stageK = [&](int k, int buf) {
        const f16* src = Wb + ((size_t)(k * CS + cs) * CH) * 512 + lane * 8;
        f16* dst = &sB[(size_t)buf * CH * 512];
#pragma unroll
        for (int c = w; c < CH; c += WAVES)
            gld_lds16(src + (size_t)c * 512, dst + (size_t)c * 512);
    };

    f32x4 acc[MROW * NTB], acc2[MROW * NTB];
#pragma unroll
    for (int i = 0; i < MROW * NTB; ++i) {
        acc[i]  = (f32x4){0.f, 0.f, 0.f, 0.f};
        acc2[i] = (f32x4){0.f, 0.f, 0.f, 0.f};
    }

    f16x8 va[MROW * KK], vl[MROW * KKL];
    f16x8 vaB[(BMODE == 0 && PIPEA) ? MROW * KK : 1];
    f16x8 vlB[(BMODE == 0 && PIPEA) ? MROW * KKL : 1];

    auto loadA = [&](int idx, f16x8* pva, f16x8* pvl) {
        const f16* arow = fin + (size_t)idx * C + h8;
#pragma unroll
        for (int kk = 0; kk < KK; ++kk) {
            pva[kk] = *(const f16x8*)(arow + kk * 32);
            if constexpr (TERMS == 2)
                pvl[kk] = *(const f16x8*)(arow + in_plane + kk * 32);
        }
    };

    auto mfmaPhase = [&](const f16x8* pva, const f16x8* pvl, int kbuf) {
        const f16* sBc = &sB[(size_t)kbuf * CH * 512] + lane * 8;
#pragma unroll
        for (int kk = 0; kk < KK; ++kk) {
#pragma unroll
            for (int nt = 0; nt < NTB; ++nt) {
                const f16* bp = sBc + (size_t)((kk * NTBT + wco * NTB + nt) * TERMS) * 512;
                const f16x8 bh = *(const f16x8*)bp;
                if constexpr (TERMS == 2) {
                    const f16x8 bl = *(const f16x8*)(bp + 512);
#pragma unroll
                    for (int r = 0; r < MROW; ++r) {
                        acc[r * NTB + nt]  = __builtin_amdgcn_mfma_f32_16x16x32_f16(
                            pva[r * KK + kk], bh, acc[r * NTB + nt], 0, 0, 0);
                        acc2[r * NTB + nt] = __builtin_amdgcn_mfma_f32_16x16x32_f16(
                            pva[r * KK + kk], bl, acc2[r * NTB + nt], 0, 0, 0);
                        acc2[r * NTB + nt] = __builtin_amdgcn_mfma_f32_16x16x32_f16(
                            pvl[r * KK + kk], bh, acc2[r * NTB + nt], 0, 0, 0);
                    }
                } else {
#pragma unroll
                    for (int r = 0; r < MROW; ++r)
                        acc[r * NTB + nt] = __builtin_amdgcn_mfma_f32_16x16x32_f16(
                            pva[r * KK + kk], bh, acc[r * NTB + nt], 0, 0, 0);
                }
            }
        }
    };

    if constexpr (BMODE == 1) {
        // ---- per-k dbuf; 1 barrier/k; A(k+1) issued pre-drain ----
        int idxN[MROW];
#pragma unroll
        for (int r = 0; r < MROW; ++r)
            loadA(nbrIdx(r, 0), &va[r * KK], &vl[r * KKL]);
        stageK(0, 0);
#pragma unroll
        for (int r = 0; r < MROW; ++r) idxN[r] = nbrIdx(r, 1);
        __syncthreads();

        for (int k = 0; k < 27; ++k) {
            if (k + 1 < 27) stageK(k + 1, (k + 1) & 1);
            mfmaPhase(va, vl, k & 1);
            if (k + 1 < 27) {
#pragma unroll
                for (int r = 0; r < MROW; ++r)
                    loadA(idxN[r], &va[r * KK], &vl[r * KKL]);
#pragma unroll
                for (int r = 0; r < MROW; ++r)
                    idxN[r] = (k + 2 < 27) ? nbrIdx(r, k + 2) : NZ;
                __syncthreads();
            }
        }
    } else if constexpr (BMODE == 2) {
        // ---- per-k single buffer; 2 barriers/k (covered by co-res block) ----
        int idxN[MROW];
#pragma unroll
        for (int r = 0; r < MROW; ++r)
            loadA(nbrIdx(r, 0), &va[r * KK], &vl[r * KKL]);
#pragma unroll
        for (int r = 0; r < MROW; ++r) idxN[r] = nbrIdx(r, 1);

        for (int k = 0; k < 27; ++k) {
            stageK(k, 0);
            __syncthreads();
            mfmaPhase(va, vl, 0);
            if (k + 1 < 27) {
#pragma unroll
                for (int r = 0; r < MROW; ++r)
                    loadA(idxN[r], &va[r * KK], &vl[r * KKL]);
#pragma unroll
                for (int r = 0; r < MROW; ++r)
                    idxN[r] = (k + 2 < 27) ? nbrIdx(r, k + 2) : NZ;
                __syncthreads();
            }
        }
    } else {
        // ---- whole-B resident, no k-loop barriers; PIPEA A reg-dbuf with
        //      MROW-deep MLP (each lane keeps MROW gathers in flight) ----
#pragma unroll
        for (int c = w; c < 27 * CH; c += WAVES)
            gld_lds16(Wb + (size_t)c * 512 + lane * 8, &sB[(size_t)c * 512]);
        int idxN[MROW];
#pragma unroll
        for (int r = 0; r < MROW; ++r)
            loadA(nbrIdx(r, 0), &va[r * KK], &vl[r * KKL]);
#pragma unroll
        for (int r = 0; r < MROW; ++r) idxN[r] = nbrIdx(r, 1);
        __syncthreads();

        if constexpr (PIPEA) {
            auto body = [&](int k, f16x8* vac, f16x8* vlc, f16x8* van, f16x8* vln) {
                if (k >= 27) return;
                if (k + 1 < 27) {
#pragma unroll
                    for (int r = 0; r < MROW; ++r)
                        loadA(idxN[r], &van[r * KK], &vln[r * KKL]);
#pragma unroll
                    for (int r = 0; r < MROW; ++r)
                        idxN[r] = (k + 2 < 27) ? nbrIdx(r, k + 2) : NZ;
                }
                mfmaPhase(vac, vlc, k);
            };
            for (int k2 = 0; k2 < 27; k2 += 2) {
                body(k2, va, vl, vaB, vlB);
                body(k2 + 1, vaB, vlB, va, vl);
            }
        } else {
            for (int k = 0; k < 27; ++k) {
                mfmaPhase(va, vl, k);
                if (k + 1 < 27) {
#pragma unroll
                    for (int r = 0; r < MROW; ++r)
                        loadA(idxN[r], &va[r * KK], &vl[r * KKL]);
#pragma unroll
                    for (int r = 0; r < MROW; ++r)
                        idxN[r] = (k + 2 < 27) ? nbrIdx(r, k + 2) : NZ;
                }
            }
        }
    }

    // ---- epilogue: D col=lane&15, row=(lane>>4)*4+j ----
    const int colg = lane & 15;
    const int rg   = lane >> 4;
#pragma unroll
    for (int r = 0; r < MROW; ++r) {
#pragma unroll
        for (int nt = 0; nt < NTB; ++nt) {
#pragma unroll
            for (int j = 0; j < 4; ++j) {
                float v = acc[r * NTB + nt][j];
                if constexpr (TERMS == 2) v += acc2[r * NTB + nt][j] * (1.f / 4096.f);
                const int n  = n0 + (wrow * MROW + r) * 16 + rg * 4 + j;
                const int co = ((cs * WCO + wco) * NTB + nt) * 16 + colg;
                if (n < Nstore && co < CO_real) {
                    if constexpr (OUTM == 0) {
                        ((float*)outv)[(size_t)n * ostride + ooff + co] = v;
                    } else if constexpr (OUTM == 1) {
                        ((f16*)outv)[(size_t)n * ostride + co] = (f16)v;
                    } else {
                        f16* o = (f16*)outv;
                        const f16 h = (f16)v;
                        o[(size_t)n * ostride + co] = h;
                        o[out_plane + (size_t)n * ostride + co] = (f16)((v - (float)h) * 4096.f);
                    }
                }
            }
        }
    }
}

// nbrm[i] = nbr[i] if that neighbor survives the attention mask, else -1.
__global__ __launch_bounds__(256)
void remap_nbr(const int* __restrict__ nbr, const float* __restrict__ att,
               int* __restrict__ nbrm, size_t total)
{
    const size_t i = (size_t)blockIdx.x * 256 + threadIdx.x;
    if (i >= total) return;
    const int j = nbr[i];
    nbrm[i] = (j >= 0 && att[j] > 0.5f) ? j : -1;
}

// ---------------------------------------------------------------------------
// P-factorized score: P[k][R][c] = f[R] @ Ws[k][:,c] as ONE dense GEMM
// f[N x C] @ Wflat[C x 54->64] (no gather). P is f32 [27][N][2].
// ---------------------------------------------------------------------------
template<int C>
__global__ __launch_bounds__(256)
void pgemm_score(const f16* __restrict__ fin, size_t plane,
                 const f16* __restrict__ Wb,   // (C/32)*4*2 chunks
                 float* __restrict__ P, int N)
{
    constexpr int KK = C / 32;
    constexpr int CH = KK * 4 * 2;
    __shared__ f16 sB[CH * 512];

    const int tid  = threadIdx.x;
    const int lane = tid & 63;
    const int w    = tid >> 6;

    const int n0 = blockIdx.x * 64;
    int site = n0 + w * 16 + (lane & 15);
    if (site > N) site = N;                 // zero row for tails
    const int h8 = (lane >> 4) * 8;

    f16x8 va[KK], vl[KK];
    const f16* arow = fin + (size_t)site * C + h8;
#pragma unroll
    for (int kk = 0; kk < KK; ++kk) {
        va[kk] = *(const f16x8*)(arow + kk * 32);
        vl[kk] = *(const f16x8*)(arow + plane + kk * 32);
    }
    for (int c = w; c < CH; c += 4)
        gld_lds16(Wb + (size_t)c * 512 + lane * 8, &sB[(size_t)c * 512]);

    f32x4 acc[4], acc2[4];
#pragma unroll
    for (int nt = 0; nt < 4; ++nt) {
        acc[nt]  = (f32x4){0.f, 0.f, 0.f, 0.f};
        acc2[nt] = (f32x4){0.f, 0.f, 0.f, 0.f};
    }
    __syncthreads();

#pragma unroll
    for (int kk = 0; kk < KK; ++kk) {
#pragma unroll
        for (int nt = 0; nt < 4; ++nt) {
            const f16* bp = &sB[(size_t)((kk * 4 + nt) * 2) * 512] + lane * 8;
            const f16x8 bh = *(const f16x8*)bp;
            const f16x8 bl = *(const f16x8*)(bp + 512);
            acc[nt]  = __builtin_amdgcn_mfma_f32_16x16x32_f16(va[kk], bh, acc[nt], 0, 0, 0);
            acc2[nt] = __builtin_amdgcn_mfma_f32_16x16x32_f16(va[kk], bl, acc2[nt], 0, 0, 0);
            acc2[nt] = __builtin_amdgcn_mfma_f32_16x16x32_f16(vl[kk], bh, acc2[nt], 0, 0, 0);
        }
    }

    const int colg = lane & 15;
    const int rg   = lane >> 4;
#pragma unroll
    for (int nt = 0; nt < 4; ++nt) {
#pragma unroll
        for (int j = 0; j < 4; ++j) {
            const float r = acc[nt][j] + acc2[nt][j] * (1.f / 4096.f);
            const int n  = n0 + w * 16 + rg * 4 + j;
            const int co = nt * 16 + colg;
            if (n < N && co < 54)
                P[(size_t)(co >> 1) * N * 2 + (size_t)n * 2 + (co & 1)] = r;
        }
    }
}

// score(S) = sum_k P[k][nbr(S,k)]  (f32, k-ordered like the reference);
// also fills the coords columns of ppn.
__global__ __launch_bounds__(256)
void reduce_score(const float* __restrict__ P, const int* __restrict__ nbr,
                  const int* __restrict__ coords, float* __restrict__ ppn, int N)
{
    const int site = blockIdx.x * 256 + threadIdx.x;
    if (site >= N) return;
    float s0 = 0.f, s1 = 0.f;
    const size_t pl = (size_t)N * 2;
#pragma unroll
    for (int k = 0; k < 27; ++k) {
        const int idx = nbr[(size_t)site * 27 + k];
        if (idx >= 0) {
            const float2 p = *(const float2*)(P + (size_t)k * pl + (size_t)idx * 2);
            s0 += p.x; s1 += p.y;
        }
    }
    float* row = ppn + (size_t)site * 6;
    const int* cr = coords + (size_t)site * 4;
    row[0] = (float)cr[0]; row[1] = (float)cr[1];
    row[2] = (float)cr[2]; row[3] = (float)cr[3];
    row[4] = s0; row[5] = s1;
}

// ---------------------------------------------------------------------------
// Pre-pass: f32 rows (optionally x att-mask) -> f16 split planes, plus a
// zero row at index N (gather target for missing neighbors / tail sites).
// ---------------------------------------------------------------------------
template<int TERMS>
__global__ __launch_bounds__(256)
void prepass(const float* __restrict__ f, const float* __restrict__ att,
             f16* __restrict__ dst, size_t plane, int C4, int N)
{
    const size_t i = (size_t)blockIdx.x * 256 + threadIdx.x;
    const size_t total = (size_t)(N + 1) * C4;
    if (i >= total) return;
    const int row = (int)(i / C4);
    float4 v = make_float4(0.f, 0.f, 0.f, 0.f);
    if (row < N) {
        v = *(const float4*)(f + i * 4);
        if (att != nullptr) {
            const float a = att[row];
            v.x *= a; v.y *= a; v.z *= a; v.w *= a;
        }
    }
    const float xs[4] = {v.x, v.y, v.z, v.w};
    f16x4 hi, lo;
#pragma unroll
    for (int j = 0; j < 4; ++j) {
        const f16 h = (f16)xs[j];
        hi[j] = h;
        lo[j] = (f16)((xs[j] - (float)h) * 4096.f);
    }
    *(f16x4*)(dst + i * 4) = hi;
    if constexpr (TERMS == 2)
        *(f16x4*)(dst + plane + i * 4) = lo;
}

// Pack fp32 W[27][C][CO_real] into 16x16 fragment chunks:
// chunk id = ((((k*CS + cs)*KK + kk)*NTB + nt)*TERMS + term), 512 f16 each.
__global__ __launch_bounds__(256)
void pack_w_f16(const float* __restrict__ W, f16* __restrict__ Wb,
                int C, int CO_real, int CS, int NTB, int TERMS)
{
    const int KK = C / 32;
    const int total = 27 * CS * KK * NTB * TERMS * 64;
    const int t = blockIdx.x * blockDim.x + threadIdx.x;
    if (t >= total) return;
    const int lane = t & 63;
    int cid = t >> 6;
    const int term = cid % TERMS; cid /= TERMS;
    const int nt   = cid % NTB;   cid /= NTB;
    const int kk   = cid % KK;    cid /= KK;
    const int cs   = cid % CS;
    const int k    = cid / CS;
    const int co   = (cs * NTB + nt) * 16 + (lane & 15);
#pragma unroll
    for (int j = 0; j < 8; ++j) {
        const int ci = kk * 32 + (lane >> 4) * 8 + j;
        const float x = (co < CO_real) ? W[((size_t)k * C + ci) * CO_real + co] : 0.f;
        const f16 h = (f16)x;
        Wb[(size_t)t * 8 + j] = (term == 0) ? h : (f16)((x - (float)h) * 4096.f);
    }
}

// Pack score weights [27][C][2] as a flat [C x 54->64] fragment set,
// chunk id = ((kk*4 + nt)*2 + term); flat col co = 2k + c.
__global__ __launch_bounds__(256)
void pack_ws_flat(const float* __restrict__ W, f16* __restrict__ Wb, int C)
{
    const int KK = C / 32;
    const int total = KK * 4 * 2 * 64;
    const int t = blockIdx.x * blockDim.x + threadIdx.x;
    if (t >= total) return;
    const int lane = t & 63;
    int cid = t >> 6;
    const int term = cid % 2;
    const int nt   = (cid >> 1) % 4;
    const int kk   = cid >> 3;
    const int co   = nt * 16 + (lane & 15);
#pragma unroll
    for (int j = 0; j < 8; ++j) {
        const int ci = kk * 32 + (lane >> 4) * 8 + j;
        const float x = (co < 54) ? W[((size_t)(co >> 1) * C + ci) * 2 + (co & 1)] : 0.f;
        const f16 h = (f16)x;
        Wb[(size_t)t * 8 + j] = (term == 0) ? h : (f16)((x - (float)h) * 4096.f);
    }
}

// Pack the fused head [27][32][{3|2|5}->10] directly into fragment chunks
// (chunk per k; single term).
__global__ __launch_bounds__(256)
void pack_wh_frag(const float* __restrict__ wp, const float* __restrict__ ws,
                  const float* __restrict__ wt, f16* __restrict__ Wb)
{
    const int t = blockIdx.x * blockDim.x + threadIdx.x;
    if (t >= 27 * 64) return;
    const int lane = t & 63;
    const int k    = t >> 6;
    const int co   = lane & 15;
#pragma unroll
    for (int j = 0; j < 8; ++j) {
        const int ci = (lane >> 4) * 8 + j;
        float x = 0.f;
        if (co < 3)       x = wp[((size_t)k * 32 + ci) * 3 + co];
        else if (co < 5)  x = ws[((size_t)k * 32 + ci) * 2 + (co - 3)];
        else if (co < 10) x = wt[((size_t)k * 32 + ci) * 5 + (co - 5)];
        Wb[(size_t)t * 8 + j] = (f16)x;
    }
}

__global__ __launch_bounds__(256)
void att_kernel(const float* __restrict__ ppn, const int* __restrict__ parent,
                float* __restrict__ att, int N)
{
    const int i = blockIdx.x * blockDim.x + threadIdx.x;
    if (i >= N) return;
    const int p = parent[i];
    const float s0 = ppn[(size_t)p * 6 + 4];
    const float s1 = ppn[(size_t)p * 6 + 5];
    const float m  = fmaxf(s0, s1);
    const float e0 = expf(s0 - m);
    const float e1 = expf(s1 - m);
    const float p1 = e1 / (e0 + e1);
    att[i] = (p1 > 0.8f) ? 1.f : 0.f;
}

extern "C" void kernel_launch(void* const* d_in, const int* in_sizes, int n_in,
                              void* d_out, int out_size, void* d_ws, size_t ws_size,
                              hipStream_t stream)
{
    const float* f1       = (const float*)d_in[0];
    const float* f2       = (const float*)d_in[1];
    const float* f3       = (const float*)d_in[2];
    const float* w1_conv  = (const float*)d_in[3];
    const float* w1_score = (const float*)d_in[4];
    const float* w2_conv  = (const float*)d_in[5];
    const float* w2_score = (const float*)d_in[6];
    const float* w3_conv  = (const float*)d_in[7];
    const float* w3_pix   = (const float*)d_in[8];
    const float* w3_score = (const float*)d_in[9];
    const float* w3_type  = (const float*)d_in[10];
    const int* coords1    = (const int*)d_in[11];
    const int* coords2    = (const int*)d_in[12];
    const int* nbr1       = (const int*)d_in[13];
    const int* nbr2       = (const int*)d_in[14];
    const int* nbr3       = (const int*)d_in[15];
    const int* parent12   = (const int*)d_in[16];
    const int* parent23   = (const int*)d_in[17];

    const int N1 = in_sizes[0] / 160;   // 20000
    const int N2 = in_sizes[1] / 96;    // 160000
    const int N3 = in_sizes[2] / 32;    // 320000

    // Output layout: points[N3,10] | ppn1[N1,6] | ppn2[N2,6] | att[N2] | att2[N3]
    float* points = (float*)d_out;
    float* ppn1   = points + (size_t)N3 * 10;
    float* ppn2   = ppn1 + (size_t)N1 * 6;
    float* attn   = ppn2 + (size_t)N2 * 6;
    float* attn2  = attn + (size_t)N2;

    // Workspace (all conv inputs have N+1 rows; row N = zeros).
    const size_t p1 = (size_t)(N1 + 1) * 160;
    const size_t p2 = (size_t)(N2 + 1) * 96;
    const size_t p3 = (size_t)(N3 + 1) * 32;
    f16* f1s  = (f16*)d_ws;           // 2*p1 = 12.8MB
    f16* xs   = f1s + 2 * p1;         // 2*p1
    f16* f2s  = xs + 2 * p1;          // 2*p2 = 61.4MB
    f16* ys   = f2s + 2 * p2;         // 2*p2
    float* P1 = (float*)f1s;          // 4.3MB  (dead after reduce1)
    int* nbr2m = (int*)f1s;           // 17.3MB <= 25.6MB (f1s+xs)
    f16* f3s  = f1s;                  // 20.5MB (after conv2)
    float* P2 = (float*)f2s;          // 34.6MB (dead after reduce2)
    f16* zs   = f2s;                  // 20.5MB
    int* nbr3m = (int*)((char*)f2s + ((p3 * 2 + 255) & ~(size_t)255));
    f16* Wb1  = ys + 2 * p2;                // 2700 chunks
    f16* Wb2  = Wb1 + (size_t)2700 * 512;   // 972
    f16* Wb3  = Wb2 + (size_t)972 * 512;    // 54
    f16* Wbh  = Wb3 + (size_t)54 * 512;     // 27
    f16* Wsf1 = Wbh + (size_t)27 * 512;     // 40 (score1 flat)
    f16* Wsf2 = Wsf1 + (size_t)40 * 512;    // 24 (score2 flat)

    // ---- weight packing ----
    pack_w_f16<<<(2700 * 64 + 255) / 256, 256, 0, stream>>>(w1_conv, Wb1, 160, 160, 2, 5, 2);
    pack_w_f16<<<(972 * 64 + 255) / 256, 256, 0, stream>>>(w2_conv, Wb2, 96, 96, 2, 3, 2);
    pack_w_f16<<<(54 * 64 + 255) / 256, 256, 0, stream>>>(w3_conv, Wb3, 32, 32, 1, 2, 1);
    pack_wh_frag<<<(27 * 64 + 255) / 256, 256, 0, stream>>>(w3_pix, w3_score, w3_type, Wbh);
    pack_ws_flat<<<(40 * 64 + 255) / 256, 256, 0, stream>>>(w1_score, Wsf1, 160);
    pack_ws_flat<<<(24 * 64 + 255) / 256, 256, 0, stream>>>(w2_score, Wsf2, 96);

    // ---- level 1 ----
    prepass<2><<<(int)(((size_t)(N1 + 1) * 40 + 255) / 256), 256, 0, stream>>>(
        f1, nullptr, f1s, p1, 40, N1);
    // conv1: C=160 NTB=5 CS=2 WCO=1 MROW=1, sbuf (50KB LDS, 2 barriers/k).
    conv_mfma<160, 5, 2, 1, 2, 8, 2, 2, 0, 1><<<160 * 2, 512, 0, stream>>>(
        f1s, p1, nbr1, Wb1, xs, 160, 0, p1, 160, N1, N1 + 1, 160);
    pgemm_score<160><<<(N1 + 63) / 64, 256, 0, stream>>>(xs, p1, Wsf1, P1, N1);
    reduce_score<<<(N1 + 255) / 256, 256, 0, stream>>>(P1, nbr1, coords1, ppn1, N1);
    att_kernel<<<(N2 + 255) / 256, 256, 0, stream>>>(ppn1, parent12, attn, N2);

    // ---- level 2 ----
    remap_nbr<<<(int)(((size_t)N2 * 27 + 255) / 256), 256, 0, stream>>>(
        nbr2, attn, nbr2m, (size_t)N2 * 27);
    prepass<2><<<(int)(((size_t)(N2 + 1) * 24 + 255) / 256), 256, 0, stream>>>(
        f2, attn, f2s, p2, 24, N2);
    // conv2: R13-proven best (NTB=3 CS=2 MROW=1 WAVES=8, 36KB dbuf, masked
    // remap). tiles=1250 -> pad 1252, nwg=2504 (%8==0). 212us measured.
    conv_mfma<96, 3, 2, 1, 2, 8, 1, 2, 0, 1><<<1252 * 2, 512, 0, stream>>>(
        f2s, p2, nbr2m, Wb2, ys, 96, 0, p2, 96, N2, N2 + 1, 1252);
    pgemm_score<96><<<(N2 + 63) / 64, 256, 0, stream>>>(ys, p2, Wsf2, P2, N2);
    reduce_score<<<(N2 + 255) / 256, 256, 0, stream>>>(P2, nbr2, coords2, ppn2, N2);
    att_kernel<<<(N3 + 255) / 256, 256, 0, stream>>>(ppn2, parent23, attn2, N3);

    // ---- level 3 (points chain, single-term f16) ----
    remap_nbr<<<(int)(((size_t)N3 * 27 + 255) / 256), 256, 0, stream>>>(
        nbr3, attn2, nbr3m, (size_t)N3 * 27);
    prepass<1><<<(int)(((size_t)(N3 + 1) * 8 + 255) / 256), 256, 0, stream>>>(
        f3, attn2, f3s, 0, 8, N3);
    // conv3: whole-B (54KB), no k barriers, PIPEA + MROW=4 (4-8 gathers in
    // flight per lane = MLP for the latency-bound gather). ROWS=512,
    // tiles=ceil(320001/512)=626 -> pad 632 (%8==0).
    conv_mfma<32, 2, 1, 1, 1, 8, 0, 1, 1, 4><<<632, 512, 0, stream>>>(
        f3s, 0, nbr3m, Wb3, zs, 32, 0, 0, 32, N3, N3 + 1, 632);
    // head: whole-B (27KB), PIPEA + MROW=4. zs NOT masked -> nbr3.
    // tiles=ceil(320000/512)=625 -> pad 632.
    conv_mfma<32, 1, 1, 1, 1, 8, 0, 0, 1, 4><<<632, 512, 0, stream>>>(
        zs, 0, nbr3, Wbh, points, 10, 0, 0, 10, N3, N3, 632);
}

// Round 16
// 598.520 us; speedup vs baseline: 1.1511x; 1.0484x over previous
//
#include <hip/hip_runtime.h>
#include <cstddef>

typedef _Float16 f16;
typedef f16 f16x4 __attribute__((ext_vector_type(4)));
typedef f16 f16x8 __attribute__((ext_vector_type(8)));
typedef float f32x4 __attribute__((ext_vector_type(4)));

// async global->LDS, 16B per lane. LDS dest = uniform base + lane*16 (HW);
// global src is per-lane.
__device__ inline void gld_lds16(const f16* g, f16* l) {
    __builtin_amdgcn_global_load_lds(
        (const __attribute__((address_space(1))) void*)g,
        (__attribute__((address_space(3))) void*)l, 16, 0, 0);
}

// ---------------------------------------------------------------------------
// 16x16x32 MFMA submanifold conv, A-direct / B-in-LDS.
//  - GEOMETRY (R5..R15 measured): conv2 best = NTB=3 CS=2 MROW=1 WAVES=8,
//    36KB dbuf (212us w/ mask remap). MROW>1 ALWAYS loses (R8/R10/R11/R15).
//    conv3/head best = whole-B BMODE=0, MROW=1, grid 2504 (R13).
//  - conv1 (R16): was 320 blocks = 1.25/CU -> single barrier group on most
//    CUs, BMODE=2's 2 barriers/k fully exposed. WAVES=4 -> 632 blocks,
//    3 blocks/CU by LDS (50KB sbuf) = 3 covering barrier groups.
//  - MASK REMAP (R13, proven): att zeroes ~84% of f2/f3 rows exactly; nbr
//    remapped so masked gathers hit the L1-resident zero row.
//  - TERMS=2: Markidis f16 split (hi + lo*2^12), 3 MFMAs/pair -> ~fp32
//    accuracy (mask-threshold chain). TERMS=1: plain f16 (points chain).
//  - Bijective XCD-chunk swizzle (nwg % 8 == 0).
// ---------------------------------------------------------------------------
template<int C, int NTB, int CS, int WCO, int TERMS, int WAVES, int BMODE,
         int OUTM, int PIPEA, int MROW>
__global__ __launch_bounds__(WAVES * 64)
void conv_mfma(const f16* __restrict__ fin, size_t in_plane,
               const int* __restrict__ nbr,
               const f16* __restrict__ Wb,
               void* __restrict__ outv, int ostride, int ooff, size_t out_plane,
               int CO_real, int N, int Nstore, int tilesPad)
{
    constexpr int KK   = C / 32;
    constexpr int KKL  = (TERMS == 2) ? KK : 1;
    constexpr int NTBT = WCO * NTB;
    constexpr int CH   = KK * NTBT * TERMS;
    constexpr int WROW = WAVES / WCO;
    constexpr int ROWS = WROW * MROW * 16;
    constexpr int BUFS = (BMODE == 0) ? 27 : ((BMODE == 1) ? 2 : 1);
    __shared__ f16 sB[BUFS * CH * 512];

    const int lane = threadIdx.x & 63;
    const int w    = threadIdx.x >> 6;
    const int wco  = w % WCO;
    const int wrow = w / WCO;
    int gid = blockIdx.x;
    { const int q = (tilesPad * CS) >> 3; gid = (gid & 7) * q + (gid >> 3); }
    const int tile = gid / CS;
    const int cs   = gid - tile * CS;
    const int n0   = tile * ROWS;
    const int NZ   = N;                          // zero row
    const int h8   = (lane >> 4) * 8;

    int  site[MROW];
    bool sv[MROW];
#pragma unroll
    for (int r = 0; r < MROW; ++r) {
        site[r] = n0 + (wrow * MROW + r) * 16 + (lane & 15);
        sv[r]   = site[r] < N;
    }

    auto nbrIdx = [&](int r, int k) -> int {
        int v = sv[r] ? nbr[(size_t)site[r] * 27 + k] : -1;
        return (v < 0) ? NZ : v;
    };

    auto stageK = [&](int k, int buf) {
        const f16* src = Wb + ((size_t)(k * CS + cs) * CH) * 512 + lane * 8;
        f16* dst = &sB[(size_t)buf * CH * 512];
#pragma unroll
        for (int c = w; c < CH; c += WAVES)
            gld_lds16(src + (size_t)c * 512, dst + (size_t)c * 512);
    };

    f32x4 acc[MROW * NTB], acc2[MROW * NTB];
#pragma unroll
    for (int i = 0; i < MROW * NTB; ++i) {
        acc[i]  = (f32x4){0.f, 0.f, 0.f, 0.f};
        acc2[i] = (f32x4){0.f, 0.f, 0.f, 0.f};
    }

    f16x8 va[MROW * KK], vl[MROW * KKL];
    f16x8 vaB[(BMODE == 0 && PIPEA) ? MROW * KK : 1];
    f16x8 vlB[(BMODE == 0 && PIPEA) ? MROW * KKL : 1];

    auto loadA = [&](int idx, f16x8* pva, f16x8* pvl) {
        const f16* arow = fin + (size_t)idx * C + h8;
#pragma unroll
        for (int kk = 0; kk < KK; ++kk) {
            pva[kk] = *(const f16x8*)(arow + kk * 32);
            if constexpr (TERMS == 2)
                pvl[kk] = *(const f16x8*)(arow + in_plane + kk * 32);
        }
    };

    auto mfmaPhase = [&](const f16x8* pva, const f16x8* pvl, int kbuf) {
        const f16* sBc = &sB[(size_t)kbuf * CH * 512] + lane * 8;
#pragma unroll
        for (int kk = 0; kk < KK; ++kk) {
#pragma unroll
            for (int nt = 0; nt < NTB; ++nt) {
                const f16* bp = sBc + (size_t)((kk * NTBT + wco * NTB + nt) * TERMS) * 512;
                const f16x8 bh = *(const f16x8*)bp;
                if constexpr (TERMS == 2) {
                    const f16x8 bl = *(const f16x8*)(bp + 512);
#pragma unroll
                    for (int r = 0; r < MROW; ++r) {
                        acc[r * NTB + nt]  = __builtin_amdgcn_mfma_f32_16x16x32_f16(
                            pva[r * KK + kk], bh, acc[r * NTB + nt], 0, 0, 0);
                        acc2[r * NTB + nt] = __builtin_amdgcn_mfma_f32_16x16x32_f16(
                            pva[r * KK + kk], bl, acc2[r * NTB + nt], 0, 0, 0);
                        acc2[r * NTB + nt] = __builtin_amdgcn_mfma_f32_16x16x32_f16(
                            pvl[r * KK + kk], bh, acc2[r * NTB + nt], 0, 0, 0);
                    }
                } else {
#pragma unroll
                    for (int r = 0; r < MROW; ++r)
                        acc[r * NTB + nt] = __builtin_amdgcn_mfma_f32_16x16x32_f16(
                            pva[r * KK + kk], bh, acc[r * NTB + nt], 0, 0, 0);
                }
            }
        }
    };

    if constexpr (BMODE == 1) {
        // ---- per-k dbuf; 1 barrier/k; A(k+1) issued pre-drain ----
        int idxN[MROW];
#pragma unroll
        for (int r = 0; r < MROW; ++r)
            loadA(nbrIdx(r, 0), &va[r * KK], &vl[r * KKL]);
        stageK(0, 0);
#pragma unroll
        for (int r = 0; r < MROW; ++r) idxN[r] = nbrIdx(r, 1);
        __syncthreads();

        for (int k = 0; k < 27; ++k) {
            if (k + 1 < 27) stageK(k + 1, (k + 1) & 1);
            mfmaPhase(va, vl, k & 1);
            if (k + 1 < 27) {
#pragma unroll
                for (int r = 0; r < MROW; ++r)
                    loadA(idxN[r], &va[r * KK], &vl[r * KKL]);
#pragma unroll
                for (int r = 0; r < MROW; ++r)
                    idxN[r] = (k + 2 < 27) ? nbrIdx(r, k + 2) : NZ;
                __syncthreads();
            }
        }
    } else if constexpr (BMODE == 2) {
        // ---- per-k single buffer; 2 barriers/k (covered by co-res blocks) ----
        int idxN[MROW];
#pragma unroll
        for (int r = 0; r < MROW; ++r)
            loadA(nbrIdx(r, 0), &va[r * KK], &vl[r * KKL]);
#pragma unroll
        for (int r = 0; r < MROW; ++r) idxN[r] = nbrIdx(r, 1);

        for (int k = 0; k < 27; ++k) {
            stageK(k, 0);
            __syncthreads();
            mfmaPhase(va, vl, 0);
            if (k + 1 < 27) {
#pragma unroll
                for (int r = 0; r < MROW; ++r)
                    loadA(idxN[r], &va[r * KK], &vl[r * KKL]);
#pragma unroll
                for (int r = 0; r < MROW; ++r)
                    idxN[r] = (k + 2 < 27) ? nbrIdx(r, k + 2) : NZ;
                __syncthreads();
            }
        }
    } else {
        // ---- whole-B resident, no k-loop barriers; PIPEA A reg-dbuf ----
#pragma unroll
        for (int c = w; c < 27 * CH; c += WAVES)
            gld_lds16(Wb + (size_t)c * 512 + lane * 8, &sB[(size_t)c * 512]);
        int idxN[MROW];
#pragma unroll
        for (int r = 0; r < MROW; ++r)
            loadA(nbrIdx(r, 0), &va[r * KK], &vl[r * KKL]);
#pragma unroll
        for (int r = 0; r < MROW; ++r) idxN[r] = nbrIdx(r, 1);
        __syncthreads();

        if constexpr (PIPEA) {
            auto body = [&](int k, f16x8* vac, f16x8* vlc, f16x8* van, f16x8* vln) {
                if (k >= 27) return;
                if (k + 1 < 27) {
#pragma unroll
                    for (int r = 0; r < MROW; ++r)
                        loadA(idxN[r], &van[r * KK], &vln[r * KKL]);
#pragma unroll
                    for (int r = 0; r < MROW; ++r)
                        idxN[r] = (k + 2 < 27) ? nbrIdx(r, k + 2) : NZ;
                }
                mfmaPhase(vac, vlc, k);
            };
            for (int k2 = 0; k2 < 27; k2 += 2) {
                body(k2, va, vl, vaB, vlB);
                body(k2 + 1, vaB, vlB, va, vl);
            }
        } else {
            for (int k = 0; k < 27; ++k) {
                mfmaPhase(va, vl, k);
                if (k + 1 < 27) {
#pragma unroll
                    for (int r = 0; r < MROW; ++r)
                        loadA(idxN[r], &va[r * KK], &vl[r * KKL]);
#pragma unroll
                    for (int r = 0; r < MROW; ++r)
                        idxN[r] = (k + 2 < 27) ? nbrIdx(r, k + 2) : NZ;
                }
            }
        }
    }

    // ---- epilogue: D col=lane&15, row=(lane>>4)*4+j ----
    const int colg = lane & 15;
    const int rg   = lane >> 4;
#pragma unroll
    for (int r = 0; r < MROW; ++r) {
#pragma unroll
        for (int nt = 0; nt < NTB; ++nt) {
#pragma unroll
            for (int j = 0; j < 4; ++j) {
                float v = acc[r * NTB + nt][j];
                if constexpr (TERMS == 2) v += acc2[r * NTB + nt][j] * (1.f / 4096.f);
                const int n  = n0 + (wrow * MROW + r) * 16 + rg * 4 + j;
                const int co = ((cs * WCO + wco) * NTB + nt) * 16 + colg;
                if (n < Nstore && co < CO_real) {
                    if constexpr (OUTM == 0) {
                        ((float*)outv)[(size_t)n * ostride + ooff + co] = v;
                    } else if constexpr (OUTM == 1) {
                        ((f16*)outv)[(size_t)n * ostride + co] = (f16)v;
                    } else {
                        f16* o = (f16*)outv;
                        const f16 h = (f16)v;
                        o[(size_t)n * ostride + co] = h;
                        o[out_plane + (size_t)n * ostride + co] = (f16)((v - (float)h) * 4096.f);
                    }
                }
            }
        }
    }
}

// nbrm[i] = nbr[i] if that neighbor survives the attention mask, else -1.
__global__ __launch_bounds__(256)
void remap_nbr(const int* __restrict__ nbr, const float* __restrict__ att,
               int* __restrict__ nbrm, size_t total)
{
    const size_t i = (size_t)blockIdx.x * 256 + threadIdx.x;
    if (i >= total) return;
    const int j = nbr[i];
    nbrm[i] = (j >= 0 && att[j] > 0.5f) ? j : -1;
}

// ---------------------------------------------------------------------------
// P-factorized score: P[k][R][c] = f[R] @ Ws[k][:,c] as ONE dense GEMM
// f[N x C] @ Wflat[C x 54->64] (no gather). P is f32 [27][N][2].
// ---------------------------------------------------------------------------
template<int C>
__global__ __launch_bounds__(256)
void pgemm_score(const f16* __restrict__ fin, size_t plane,
                 const f16* __restrict__ Wb,   // (C/32)*4*2 chunks
                 float* __restrict__ P, int N)
{
    constexpr int KK = C / 32;
    constexpr int CH = KK * 4 * 2;
    __shared__ f16 sB[CH * 512];

    const int tid  = threadIdx.x;
    const int lane = tid & 63;
    const int w    = tid >> 6;

    const int n0 = blockIdx.x * 64;
    int site = n0 + w * 16 + (lane & 15);
    if (site > N) site = N;                 // zero row for tails
    const int h8 = (lane >> 4) * 8;

    f16x8 va[KK], vl[KK];
    const f16* arow = fin + (size_t)site * C + h8;
#pragma unroll
    for (int kk = 0; kk < KK; ++kk) {
        va[kk] = *(const f16x8*)(arow + kk * 32);
        vl[kk] = *(const f16x8*)(arow + plane + kk * 32);
    }
    for (int c = w; c < CH; c += 4)
        gld_lds16(Wb + (size_t)c * 512 + lane * 8, &sB[(size_t)c * 512]);

    f32x4 acc[4], acc2[4];
#pragma unroll
    for (int nt = 0; nt < 4; ++nt) {
        acc[nt]  = (f32x4){0.f, 0.f, 0.f, 0.f};
        acc2[nt] = (f32x4){0.f, 0.f, 0.f, 0.f};
    }
    __syncthreads();

#pragma unroll
    for (int kk = 0; kk < KK; ++kk) {
#pragma unroll
        for (int nt = 0; nt < 4; ++nt) {
            const f16* bp = &sB[(size_t)((kk * 4 + nt) * 2) * 512] + lane * 8;
            const f16x8 bh = *(const f16x8*)bp;
            const f16x8 bl = *(const f16x8*)(bp + 512);
            acc[nt]  = __builtin_amdgcn_mfma_f32_16x16x32_f16(va[kk], bh, acc[nt], 0, 0, 0);
            acc2[nt] = __builtin_amdgcn_mfma_f32_16x16x32_f16(va[kk], bl, acc2[nt], 0, 0, 0);
            acc2[nt] = __builtin_amdgcn_mfma_f32_16x16x32_f16(vl[kk], bh, acc2[nt], 0, 0, 0);
        }
    }

    const int colg = lane & 15;
    const int rg   = lane >> 4;
#pragma unroll
    for (int nt = 0; nt < 4; ++nt) {
#pragma unroll
        for (int j = 0; j < 4; ++j) {
            const float r = acc[nt][j] + acc2[nt][j] * (1.f / 4096.f);
            const int n  = n0 + w * 16 + rg * 4 + j;
            const int co = nt * 16 + colg;
            if (n < N && co < 54)
                P[(size_t)(co >> 1) * N * 2 + (size_t)n * 2 + (co & 1)] = r;
        }
    }
}

// score(S) = sum_k P[k][nbr(S,k)]  (f32, k-ordered like the reference);
// also fills the coords columns of ppn.
__global__ __launch_bounds__(256)
void reduce_score(const float* __restrict__ P, const int* __restrict__ nbr,
                  const int* __restrict__ coords, float* __restrict__ ppn, int N)
{
    const int site = blockIdx.x * 256 + threadIdx.x;
    if (site >= N) return;
    float s0 = 0.f, s1 = 0.f;
    const size_t pl = (size_t)N * 2;
#pragma unroll
    for (int k = 0; k < 27; ++k) {
        const int idx = nbr[(size_t)site * 27 + k];
        if (idx >= 0) {
            const float2 p = *(const float2*)(P + (size_t)k * pl + (size_t)idx * 2);
            s0 += p.x; s1 += p.y;
        }
    }
    float* row = ppn + (size_t)site * 6;
    const int* cr = coords + (size_t)site * 4;
    row[0] = (float)cr[0]; row[1] = (float)cr[1];
    row[2] = (float)cr[2]; row[3] = (float)cr[3];
    row[4] = s0; row[5] = s1;
}

// ---------------------------------------------------------------------------
// Pre-pass: f32 rows (optionally x att-mask) -> f16 split planes, plus a
// zero row at index N (gather target for missing neighbors / tail sites).
// ---------------------------------------------------------------------------
template<int TERMS>
__global__ __launch_bounds__(256)
void prepass(const float* __restrict__ f, const float* __restrict__ att,
             f16* __restrict__ dst, size_t plane, int C4, int N)
{
    const size_t i = (size_t)blockIdx.x * 256 + threadIdx.x;
    const size_t total = (size_t)(N + 1) * C4;
    if (i >= total) return;
    const int row = (int)(i / C4);
    float4 v = make_float4(0.f, 0.f, 0.f, 0.f);
    if (row < N) {
        v = *(const float4*)(f + i * 4);
        if (att != nullptr) {
            const float a = att[row];
            v.x *= a; v.y *= a; v.z *= a; v.w *= a;
        }
    }
    const float xs[4] = {v.x, v.y, v.z, v.w};
    f16x4 hi, lo;
#pragma unroll
    for (int j = 0; j < 4; ++j) {
        const f16 h = (f16)xs[j];
        hi[j] = h;
        lo[j] = (f16)((xs[j] - (float)h) * 4096.f);
    }
    *(f16x4*)(dst + i * 4) = hi;
    if constexpr (TERMS == 2)
        *(f16x4*)(dst + plane + i * 4) = lo;
}

// Pack fp32 W[27][C][CO_real] into 16x16 fragment chunks:
// chunk id = ((((k*CS + cs)*KK + kk)*NTB + nt)*TERMS + term), 512 f16 each.
__global__ __launch_bounds__(256)
void pack_w_f16(const float* __restrict__ W, f16* __restrict__ Wb,
                int C, int CO_real, int CS, int NTB, int TERMS)
{
    const int KK = C / 32;
    const int total = 27 * CS * KK * NTB * TERMS * 64;
    const int t = blockIdx.x * blockDim.x + threadIdx.x;
    if (t >= total) return;
    const int lane = t & 63;
    int cid = t >> 6;
    const int term = cid % TERMS; cid /= TERMS;
    const int nt   = cid % NTB;   cid /= NTB;
    const int kk   = cid % KK;    cid /= KK;
    const int cs   = cid % CS;
    const int k    = cid / CS;
    const int co   = (cs * NTB + nt) * 16 + (lane & 15);
#pragma unroll
    for (int j = 0; j < 8; ++j) {
        const int ci = kk * 32 + (lane >> 4) * 8 + j;
        const float x = (co < CO_real) ? W[((size_t)k * C + ci) * CO_real + co] : 0.f;
        const f16 h = (f16)x;
        Wb[(size_t)t * 8 + j] = (term == 0) ? h : (f16)((x - (float)h) * 4096.f);
    }
}

// Pack score weights [27][C][2] as a flat [C x 54->64] fragment set,
// chunk id = ((kk*4 + nt)*2 + term); flat col co = 2k + c.
__global__ __launch_bounds__(256)
void pack_ws_flat(const float* __restrict__ W, f16* __restrict__ Wb, int C)
{
    const int KK = C / 32;
    const int total = KK * 4 * 2 * 64;
    const int t = blockIdx.x * blockDim.x + threadIdx.x;
    if (t >= total) return;
    const int lane = t & 63;
    int cid = t >> 6;
    const int term = cid % 2;
    const int nt   = (cid >> 1) % 4;
    const int kk   = cid >> 3;
    const int co   = nt * 16 + (lane & 15);
#pragma unroll
    for (int j = 0; j < 8; ++j) {
        const int ci = kk * 32 + (lane >> 4) * 8 + j;
        const float x = (co < 54) ? W[((size_t)(co >> 1) * C + ci) * 2 + (co & 1)] : 0.f;
        const f16 h = (f16)x;
        Wb[(size_t)t * 8 + j] = (term == 0) ? h : (f16)((x - (float)h) * 4096.f);
    }
}

// Pack the fused head [27][32][{3|2|5}->10] directly into fragment chunks
// (chunk per k; single term).
__global__ __launch_bounds__(256)
void pack_wh_frag(const float* __restrict__ wp, const float* __restrict__ ws,
                  const float* __restrict__ wt, f16* __restrict__ Wb)
{
    const int t = blockIdx.x * blockDim.x + threadIdx.x;
    if (t >= 27 * 64) return;
    const int lane = t & 63;
    const int k    = t >> 6;
    const int co   = lane & 15;
#pragma unroll
    for (int j = 0; j < 8; ++j) {
        const int ci = (lane >> 4) * 8 + j;
        float x = 0.f;
        if (co < 3)       x = wp[((size_t)k * 32 + ci) * 3 + co];
        else if (co < 5)  x = ws[((size_t)k * 32 + ci) * 2 + (co - 3)];
        else if (co < 10) x = wt[((size_t)k * 32 + ci) * 5 + (co - 5)];
        Wb[(size_t)t * 8 + j] = (f16)x;
    }
}

__global__ __launch_bounds__(256)
void att_kernel(const float* __restrict__ ppn, const int* __restrict__ parent,
                float* __restrict__ att, int N)
{
    const int i = blockIdx.x * blockDim.x + threadIdx.x;
    if (i >= N) return;
    const int p = parent[i];
    const float s0 = ppn[(size_t)p * 6 + 4];
    const float s1 = ppn[(size_t)p * 6 + 5];
    const float m  = fmaxf(s0, s1);
    const float e0 = expf(s0 - m);
    const float e1 = expf(s1 - m);
    const float p1 = e1 / (e0 + e1);
    att[i] = (p1 > 0.8f) ? 1.f : 0.f;
}

extern "C" void kernel_launch(void* const* d_in, const int* in_sizes, int n_in,
                              void* d_out, int out_size, void* d_ws, size_t ws_size,
                              hipStream_t stream)
{
    const float* f1       = (const float*)d_in[0];
    const float* f2       = (const float*)d_in[1];
    const float* f3       = (const float*)d_in[2];
    const float* w1_conv  = (const float*)d_in[3];
    const float* w1_score = (const float*)d_in[4];
    const float* w2_conv  = (const float*)d_in[5];
    const float* w2_score = (const float*)d_in[6];
    const float* w3_conv  = (const float*)d_in[7];
    const float* w3_pix   = (const float*)d_in[8];
    const float* w3_score = (const float*)d_in[9];
    const float* w3_type  = (const float*)d_in[10];
    const int* coords1    = (const int*)d_in[11];
    const int* coords2    = (const int*)d_in[12];
    const int* nbr1       = (const int*)d_in[13];
    const int* nbr2       = (const int*)d_in[14];
    const int* nbr3       = (const int*)d_in[15];
    const int* parent12   = (const int*)d_in[16];
    const int* parent23   = (const int*)d_in[17];

    const int N1 = in_sizes[0] / 160;   // 20000
    const int N2 = in_sizes[1] / 96;    // 160000
    const int N3 = in_sizes[2] / 32;    // 320000

    // Output layout: points[N3,10] | ppn1[N1,6] | ppn2[N2,6] | att[N2] | att2[N3]
    float* points = (float*)d_out;
    float* ppn1   = points + (size_t)N3 * 10;
    float* ppn2   = ppn1 + (size_t)N1 * 6;
    float* attn   = ppn2 + (size_t)N2 * 6;
    float* attn2  = attn + (size_t)N2;

    // Workspace (all conv inputs have N+1 rows; row N = zeros).
    const size_t p1 = (size_t)(N1 + 1) * 160;
    const size_t p2 = (size_t)(N2 + 1) * 96;
    const size_t p3 = (size_t)(N3 + 1) * 32;
    f16* f1s  = (f16*)d_ws;           // 2*p1 = 12.8MB
    f16* xs   = f1s + 2 * p1;         // 2*p1
    f16* f2s  = xs + 2 * p1;          // 2*p2 = 61.4MB
    f16* ys   = f2s + 2 * p2;         // 2*p2
    float* P1 = (float*)f1s;          // 4.3MB  (dead after reduce1)
    int* nbr2m = (int*)f1s;           // 17.3MB <= 25.6MB (f1s+xs)
    f16* f3s  = f1s;                  // 20.5MB (after conv2)
    float* P2 = (float*)f2s;          // 34.6MB (dead after reduce2)
    f16* zs   = f2s;                  // 20.5MB
    int* nbr3m = (int*)((char*)f2s + ((p3 * 2 + 255) & ~(size_t)255));
    f16* Wb1  = ys + 2 * p2;                // 2700 chunks
    f16* Wb2  = Wb1 + (size_t)2700 * 512;   // 972
    f16* Wb3  = Wb2 + (size_t)972 * 512;    // 54
    f16* Wbh  = Wb3 + (size_t)54 * 512;     // 27
    f16* Wsf1 = Wbh + (size_t)27 * 512;     // 40 (score1 flat)
    f16* Wsf2 = Wsf1 + (size_t)40 * 512;    // 24 (score2 flat)

    // ---- weight packing ----
    pack_w_f16<<<(2700 * 64 + 255) / 256, 256, 0, stream>>>(w1_conv, Wb1, 160, 160, 2, 5, 2);
    pack_w_f16<<<(972 * 64 + 255) / 256, 256, 0, stream>>>(w2_conv, Wb2, 96, 96, 2, 3, 2);
    pack_w_f16<<<(54 * 64 + 255) / 256, 256, 0, stream>>>(w3_conv, Wb3, 32, 32, 1, 2, 1);
    pack_wh_frag<<<(27 * 64 + 255) / 256, 256, 0, stream>>>(w3_pix, w3_score, w3_type, Wbh);
    pack_ws_flat<<<(40 * 64 + 255) / 256, 256, 0, stream>>>(w1_score, Wsf1, 160);
    pack_ws_flat<<<(24 * 64 + 255) / 256, 256, 0, stream>>>(w2_score, Wsf2, 96);

    // ---- level 1 ----
    prepass<2><<<(int)(((size_t)(N1 + 1) * 40 + 255) / 256), 256, 0, stream>>>(
        f1, nullptr, f1s, p1, 40, N1);
    // conv1: C=160 NTB=5 CS=2 WCO=1 MROW=1, sbuf (50KB LDS, 2 barriers/k),
    // WAVES=4 (R16): 632 blocks, 3 blocks/CU by LDS -> 3 covering barrier
    // groups (was 320 blocks = 1.25/CU, drains exposed). ROWS=64,
    // tiles=313 -> pad 316, nwg=632 (%8==0).
    conv_mfma<160, 5, 2, 1, 2, 4, 2, 2, 0, 1><<<316 * 2, 256, 0, stream>>>(
        f1s, p1, nbr1, Wb1, xs, 160, 0, p1, 160, N1, N1 + 1, 316);
    pgemm_score<160><<<(N1 + 63) / 64, 256, 0, stream>>>(xs, p1, Wsf1, P1, N1);
    reduce_score<<<(N1 + 255) / 256, 256, 0, stream>>>(P1, nbr1, coords1, ppn1, N1);
    att_kernel<<<(N2 + 255) / 256, 256, 0, stream>>>(ppn1, parent12, attn, N2);

    // ---- level 2 ----
    remap_nbr<<<(int)(((size_t)N2 * 27 + 255) / 256), 256, 0, stream>>>(
        nbr2, attn, nbr2m, (size_t)N2 * 27);
    prepass<2><<<(int)(((size_t)(N2 + 1) * 24 + 255) / 256), 256, 0, stream>>>(
        f2, attn, f2s, p2, 24, N2);
    // conv2: R13-proven best (NTB=3 CS=2 MROW=1 WAVES=8, 36KB dbuf, masked
    // remap). tiles=1250 -> pad 1252, nwg=2504 (%8==0). 212us measured.
    conv_mfma<96, 3, 2, 1, 2, 8, 1, 2, 0, 1><<<1252 * 2, 512, 0, stream>>>(
        f2s, p2, nbr2m, Wb2, ys, 96, 0, p2, 96, N2, N2 + 1, 1252);
    pgemm_score<96><<<(N2 + 63) / 64, 256, 0, stream>>>(ys, p2, Wsf2, P2, N2);
    reduce_score<<<(N2 + 255) / 256, 256, 0, stream>>>(P2, nbr2, coords2, ppn2, N2);
    att_kernel<<<(N3 + 255) / 256, 256, 0, stream>>>(ppn2, parent23, attn2, N3);

    // ---- level 3 (points chain, single-term f16) — R13-exact config ----
    remap_nbr<<<(int)(((size_t)N3 * 27 + 255) / 256), 256, 0, stream>>>(
        nbr3, attn2, nbr3m, (size_t)N3 * 27);
    prepass<1><<<(int)(((size_t)(N3 + 1) * 8 + 255) / 256), 256, 0, stream>>>(
        f3, attn2, f3s, 0, 8, N3);
    // conv3: C=32 NTB=2 whole-B (54KB), no k barriers, PIPEA, MROW=1; masked.
    conv_mfma<32, 2, 1, 1, 1, 8, 0, 1, 1, 1><<<2504, 512, 0, stream>>>(
        f3s, 0, nbr3m, Wb3, zs, 32, 0, 0, 32, N3, N3 + 1, 2504);
    // head: C=32 NTB=1 whole-B (27KB), PIPEA, MROW=1. zs NOT masked -> nbr3.
    conv_mfma<32, 1, 1, 1, 1, 8, 0, 0, 1, 1><<<2504, 512, 0, stream>>>(
        zs, 0, nbr3, Wbh, points, 10, 0, 0, 10, N3, N3, 2504);
}

// Round 17
// 503.152 us; speedup vs baseline: 1.3692x; 1.1895x over previous
//
#include <hip/hip_runtime.h>
#include <cstddef>

typedef _Float16 f16;
typedef f16 f16x4 __attribute__((ext_vector_type(4)));
typedef f16 f16x8 __attribute__((ext_vector_type(8)));
typedef float f32x4 __attribute__((ext_vector_type(4)));

// async global->LDS, 16B per lane. LDS dest = uniform base + lane*16 (HW);
// global src is per-lane.
__device__ inline void gld_lds16(const f16* g, f16* l) {
    __builtin_amdgcn_global_load_lds(
        (const __attribute__((address_space(1))) void*)g,
        (__attribute__((address_space(3))) void*)l, 16, 0, 0);
}

// ---------------------------------------------------------------------------
// 16x16x32 MFMA submanifold conv, A-direct / B-in-LDS.
//  - GEOMETRY (R5..R16 measured): conv2 best = NTB=3 CS=2 MROW=1 WAVES=8,
//    36KB dbuf. conv1 best = sbuf WAVES=4 (3 covering barrier groups/CU).
//    conv3/head = whole-B BMODE=0 MROW=1 grid 2504. MROW>1 always loses.
//  - MASK REMAP (R13): att zeroes ~84% of f2/f3 rows exactly; nbr remapped so
//    masked gathers hit the L1-resident zero row (conv2 FETCH 71.7->15.7MB).
//  - SKIPZ (R17): wave's 16 sites = children of 2 parents; mask is
//    per-parent, so P(all 16 gathered rows == zero row) ~ 0.5 per (wave,k).
//    One __all ballot skips the A-loads + 6 ds_read_b128 + 9 MFMAs for that
//    k -- directly attacks the LDS-read bound (~185us of conv2's 212).
//    Exact: skipped contribution is identically zero. Barriers still hit.
//  - TERMS=2: Markidis f16 split (hi + lo*2^12), 3 MFMAs/pair -> ~fp32
//    accuracy (mask-threshold chain). TERMS=1: plain f16 (points chain).
//  - Bijective XCD-chunk swizzle (nwg % 8 == 0).
// ---------------------------------------------------------------------------
template<int C, int NTB, int CS, int WCO, int TERMS, int WAVES, int BMODE,
         int OUTM, int PIPEA, int MROW, int SKIPZ>
__global__ __launch_bounds__(WAVES * 64)
void conv_mfma(const f16* __restrict__ fin, size_t in_plane,
               const int* __restrict__ nbr,
               const f16* __restrict__ Wb,
               void* __restrict__ outv, int ostride, int ooff, size_t out_plane,
               int CO_real, int N, int Nstore, int tilesPad)
{
    constexpr int KK   = C / 32;
    constexpr int KKL  = (TERMS == 2) ? KK : 1;
    constexpr int NTBT = WCO * NTB;
    constexpr int CH   = KK * NTBT * TERMS;
    constexpr int WROW = WAVES / WCO;
    constexpr int ROWS = WROW * MROW * 16;
    constexpr int BUFS = (BMODE == 0) ? 27 : ((BMODE == 1) ? 2 : 1);
    __shared__ f16 sB[BUFS * CH * 512];

    const int lane = threadIdx.x & 63;
    const int w    = threadIdx.x >> 6;
    const int wco  = w % WCO;
    const int wrow = w / WCO;
    int gid = blockIdx.x;
    { const int q = (tilesPad * CS) >> 3; gid = (gid & 7) * q + (gid >> 3); }
    const int tile = gid / CS;
    const int cs   = gid - tile * CS;
    const int n0   = tile * ROWS;
    const int NZ   = N;                          // zero row
    const int h8   = (lane >> 4) * 8;

    int  site[MROW];
    bool sv[MROW];
#pragma unroll
    for (int r = 0; r < MROW; ++r) {
        site[r] = n0 + (wrow * MROW + r) * 16 + (lane & 15);
        sv[r]   = site[r] < N;
    }

    auto nbrIdx = [&](int r, int k) -> int {
        int v = sv[r] ? nbr[(size_t)site[r] * 27 + k] : -1;
        return (v < 0) ? NZ : v;
    };

    // Wave-uniform: true iff every gathered row of this wave is the zero row.
    auto allNZ = [&](const int* ix) -> bool {
        if constexpr (!SKIPZ) return false;
        int m = 1;
#pragma unroll
        for (int r = 0; r < MROW; ++r) m &= (ix[r] == NZ);
        return __all(m);
    };

    auto stageK = [&](int k, int buf) {
        const f16* src = Wb + ((size_t)(k * CS + cs) * CH) * 512 + lane * 8;
        f16* dst = &sB[(size_t)buf * CH * 512];
#pragma unroll
        for (int c = w; c < CH; c += WAVES)
            gld_lds16(src + (size_t)c * 512, dst + (size_t)c * 512);
    };

    f32x4 acc[MROW * NTB], acc2[MROW * NTB];
#pragma unroll
    for (int i = 0; i < MROW * NTB; ++i) {
        acc[i]  = (f32x4){0.f, 0.f, 0.f, 0.f};
        acc2[i] = (f32x4){0.f, 0.f, 0.f, 0.f};
    }

    f16x8 va[MROW * KK], vl[MROW * KKL];
    f16x8 vaB[(BMODE == 0 && PIPEA) ? MROW * KK : 1];
    f16x8 vlB[(BMODE == 0 && PIPEA) ? MROW * KKL : 1];

    auto loadA = [&](int idx, f16x8* pva, f16x8* pvl) {
        const f16* arow = fin + (size_t)idx * C + h8;
#pragma unroll
        for (int kk = 0; kk < KK; ++kk) {
            pva[kk] = *(const f16x8*)(arow + kk * 32);
            if constexpr (TERMS == 2)
                pvl[kk] = *(const f16x8*)(arow + in_plane + kk * 32);
        }
    };

    auto mfmaPhase = [&](const f16x8* pva, const f16x8* pvl, int kbuf) {
        const f16* sBc = &sB[(size_t)kbuf * CH * 512] + lane * 8;
#pragma unroll
        for (int kk = 0; kk < KK; ++kk) {
#pragma unroll
            for (int nt = 0; nt < NTB; ++nt) {
                const f16* bp = sBc + (size_t)((kk * NTBT + wco * NTB + nt) * TERMS) * 512;
                const f16x8 bh = *(const f16x8*)bp;
                if constexpr (TERMS == 2) {
                    const f16x8 bl = *(const f16x8*)(bp + 512);
#pragma unroll
                    for (int r = 0; r < MROW; ++r) {
                        acc[r * NTB + nt]  = __builtin_amdgcn_mfma_f32_16x16x32_f16(
                            pva[r * KK + kk], bh, acc[r * NTB + nt], 0, 0, 0);
                        acc2[r * NTB + nt] = __builtin_amdgcn_mfma_f32_16x16x32_f16(
                            pva[r * KK + kk], bl, acc2[r * NTB + nt], 0, 0, 0);
                        acc2[r * NTB + nt] = __builtin_amdgcn_mfma_f32_16x16x32_f16(
                            pvl[r * KK + kk], bh, acc2[r * NTB + nt], 0, 0, 0);
                    }
                } else {
#pragma unroll
                    for (int r = 0; r < MROW; ++r)
                        acc[r * NTB + nt] = __builtin_amdgcn_mfma_f32_16x16x32_f16(
                            pva[r * KK + kk], bh, acc[r * NTB + nt], 0, 0, 0);
                }
            }
        }
    };

    if constexpr (BMODE == 1) {
        // ---- per-k dbuf; 1 barrier/k; A(k+1) issued pre-drain; SKIPZ ----
        int idxN[MROW];
        bool skipC, skipN;
        {
            int idx0[MROW];
#pragma unroll
            for (int r = 0; r < MROW; ++r) idx0[r] = nbrIdx(r, 0);
            skipC = allNZ(idx0);
            if (!skipC)
#pragma unroll
                for (int r = 0; r < MROW; ++r)
                    loadA(idx0[r], &va[r * KK], &vl[r * KKL]);
        }
        stageK(0, 0);
#pragma unroll
        for (int r = 0; r < MROW; ++r) idxN[r] = nbrIdx(r, 1);
        skipN = allNZ(idxN);
        __syncthreads();

        for (int k = 0; k < 27; ++k) {
            if (k + 1 < 27) stageK(k + 1, (k + 1) & 1);
            if (!skipC) mfmaPhase(va, vl, k & 1);
            if (k + 1 < 27) {
                if (!skipN)
#pragma unroll
                    for (int r = 0; r < MROW; ++r)
                        loadA(idxN[r], &va[r * KK], &vl[r * KKL]);
                skipC = skipN;
#pragma unroll
                for (int r = 0; r < MROW; ++r)
                    idxN[r] = (k + 2 < 27) ? nbrIdx(r, k + 2) : NZ;
                skipN = allNZ(idxN);
                __syncthreads();
            }
        }
    } else if constexpr (BMODE == 2) {
        // ---- per-k single buffer; 2 barriers/k (covered by co-res blocks) ----
        int idxN[MROW];
#pragma unroll
        for (int r = 0; r < MROW; ++r)
            loadA(nbrIdx(r, 0), &va[r * KK], &vl[r * KKL]);
#pragma unroll
        for (int r = 0; r < MROW; ++r) idxN[r] = nbrIdx(r, 1);

        for (int k = 0; k < 27; ++k) {
            stageK(k, 0);
            __syncthreads();
            mfmaPhase(va, vl, 0);
            if (k + 1 < 27) {
#pragma unroll
                for (int r = 0; r < MROW; ++r)
                    loadA(idxN[r], &va[r * KK], &vl[r * KKL]);
#pragma unroll
                for (int r = 0; r < MROW; ++r)
                    idxN[r] = (k + 2 < 27) ? nbrIdx(r, k + 2) : NZ;
                __syncthreads();
            }
        }
    } else {
        // ---- whole-B resident, no k-loop barriers; PIPEA A reg-dbuf; SKIPZ ----
#pragma unroll
        for (int c = w; c < 27 * CH; c += WAVES)
            gld_lds16(Wb + (size_t)c * 512 + lane * 8, &sB[(size_t)c * 512]);
        int idxN[MROW];
        bool skipC, skipN;
        {
            int idx0[MROW];
#pragma unroll
            for (int r = 0; r < MROW; ++r) idx0[r] = nbrIdx(r, 0);
            skipC = allNZ(idx0);
            if (!skipC)
#pragma unroll
                for (int r = 0; r < MROW; ++r)
                    loadA(idx0[r], &va[r * KK], &vl[r * KKL]);
        }
#pragma unroll
        for (int r = 0; r < MROW; ++r) idxN[r] = nbrIdx(r, 1);
        skipN = allNZ(idxN);
        __syncthreads();

        if constexpr (PIPEA) {
            auto body = [&](int k, f16x8* vac, f16x8* vlc, f16x8* van, f16x8* vln) {
                if (k >= 27) return;
                bool nextC = skipN;
                if (k + 1 < 27) {
                    if (!skipN)
#pragma unroll
                        for (int r = 0; r < MROW; ++r)
                            loadA(idxN[r], &van[r * KK], &vln[r * KKL]);
#pragma unroll
                    for (int r = 0; r < MROW; ++r)
                        idxN[r] = (k + 2 < 27) ? nbrIdx(r, k + 2) : NZ;
                    skipN = allNZ(idxN);
                }
                if (!skipC) mfmaPhase(vac, vlc, k);
                skipC = nextC;
            };
            for (int k2 = 0; k2 < 27; k2 += 2) {
                body(k2, va, vl, vaB, vlB);
                body(k2 + 1, vaB, vlB, va, vl);
            }
        } else {
            for (int k = 0; k < 27; ++k) {
                if (!skipC) mfmaPhase(va, vl, k);
                if (k + 1 < 27) {
                    if (!skipN)
#pragma unroll
                        for (int r = 0; r < MROW; ++r)
                            loadA(idxN[r], &va[r * KK], &vl[r * KKL]);
                    skipC = skipN;
#pragma unroll
                    for (int r = 0; r < MROW; ++r)
                        idxN[r] = (k + 2 < 27) ? nbrIdx(r, k + 2) : NZ;
                    skipN = allNZ(idxN);
                }
            }
        }
    }

    // ---- epilogue: D col=lane&15, row=(lane>>4)*4+j ----
    const int colg = lane & 15;
    const int rg   = lane >> 4;
#pragma unroll
    for (int r = 0; r < MROW; ++r) {
#pragma unroll
        for (int nt = 0; nt < NTB; ++nt) {
#pragma unroll
            for (int j = 0; j < 4; ++j) {
                float v = acc[r * NTB + nt][j];
                if constexpr (TERMS == 2) v += acc2[r * NTB + nt][j] * (1.f / 4096.f);
                const int n  = n0 + (wrow * MROW + r) * 16 + rg * 4 + j;
                const int co = ((cs * WCO + wco) * NTB + nt) * 16 + colg;
                if (n < Nstore && co < CO_real) {
                    if constexpr (OUTM == 0) {
                        ((float*)outv)[(size_t)n * ostride + ooff + co] = v;
                    } else if constexpr (OUTM == 1) {
                        ((f16*)outv)[(size_t)n * ostride + co] = (f16)v;
                    } else {
                        f16* o = (f16*)outv;
                        const f16 h = (f16)v;
                        o[(size_t)n * ostride + co] = h;
                        o[out_plane + (size_t)n * ostride + co] = (f16)((v - (float)h) * 4096.f);
                    }
                }
            }
        }
    }
}

// nbrm[i] = nbr[i] if that neighbor survives the attention mask, else -1.
__global__ __launch_bounds__(256)
void remap_nbr(const int* __restrict__ nbr, const float* __restrict__ att,
               int* __restrict__ nbrm, size_t total)
{
    const size_t i = (size_t)blockIdx.x * 256 + threadIdx.x;
    if (i >= total) return;
    const int j = nbr[i];
    nbrm[i] = (j >= 0 && att[j] > 0.5f) ? j : -1;
}

// ---------------------------------------------------------------------------
// P-factorized score: P[k][R][c] = f[R] @ Ws[k][:,c] as ONE dense GEMM
// f[N x C] @ Wflat[C x 54->64] (no gather). P is f32 [27][N][2].
// ---------------------------------------------------------------------------
template<int C>
__global__ __launch_bounds__(256)
void pgemm_score(const f16* __restrict__ fin, size_t plane,
                 const f16* __restrict__ Wb,   // (C/32)*4*2 chunks
                 float* __restrict__ P, int N)
{
    constexpr int KK = C / 32;
    constexpr int CH = KK * 4 * 2;
    __shared__ f16 sB[CH * 512];

    const int tid  = threadIdx.x;
    const int lane = tid & 63;
    const int w    = tid >> 6;

    const int n0 = blockIdx.x * 64;
    int site = n0 + w * 16 + (lane & 15);
    if (site > N) site = N;                 // zero row for tails
    const int h8 = (lane >> 4) * 8;

    f16x8 va[KK], vl[KK];
    const f16* arow = fin + (size_t)site * C + h8;
#pragma unroll
    for (int kk = 0; kk < KK; ++kk) {
        va[kk] = *(const f16x8*)(arow + kk * 32);
        vl[kk] = *(const f16x8*)(arow + plane + kk * 32);
    }
    for (int c = w; c < CH; c += 4)
        gld_lds16(Wb + (size_t)c * 512 + lane * 8, &sB[(size_t)c * 512]);

    f32x4 acc[4], acc2[4];
#pragma unroll
    for (int nt = 0; nt < 4; ++nt) {
        acc[nt]  = (f32x4){0.f, 0.f, 0.f, 0.f};
        acc2[nt] = (f32x4){0.f, 0.f, 0.f, 0.f};
    }
    __syncthreads();

#pragma unroll
    for (int kk = 0; kk < KK; ++kk) {
#pragma unroll
        for (int nt = 0; nt < 4; ++nt) {
            const f16* bp = &sB[(size_t)((kk * 4 + nt) * 2) * 512] + lane * 8;
            const f16x8 bh = *(const f16x8*)bp;
            const f16x8 bl = *(const f16x8*)(bp + 512);
            acc[nt]  = __builtin_amdgcn_mfma_f32_16x16x32_f16(va[kk], bh, acc[nt], 0, 0, 0);
            acc2[nt] = __builtin_amdgcn_mfma_f32_16x16x32_f16(va[kk], bl, acc2[nt], 0, 0, 0);
            acc2[nt] = __builtin_amdgcn_mfma_f32_16x16x32_f16(vl[kk], bh, acc2[nt], 0, 0, 0);
        }
    }

    const int colg = lane & 15;
    const int rg   = lane >> 4;
#pragma unroll
    for (int nt = 0; nt < 4; ++nt) {
#pragma unroll
        for (int j = 0; j < 4; ++j) {
            const float r = acc[nt][j] + acc2[nt][j] * (1.f / 4096.f);
            const int n  = n0 + w * 16 + rg * 4 + j;
            const int co = nt * 16 + colg;
            if (n < N && co < 54)
                P[(size_t)(co >> 1) * N * 2 + (size_t)n * 2 + (co & 1)] = r;
        }
    }
}

// score(S) = sum_k P[k][nbr(S,k)]  (f32, k-ordered like the reference);
// also fills the coords columns of ppn.
__global__ __launch_bounds__(256)
void reduce_score(const float* __restrict__ P, const int* __restrict__ nbr,
                  const int* __restrict__ coords, float* __restrict__ ppn, int N)
{
    const int site = blockIdx.x * 256 + threadIdx.x;
    if (site >= N) return;
    float s0 = 0.f, s1 = 0.f;
    const size_t pl = (size_t)N * 2;
#pragma unroll
    for (int k = 0; k < 27; ++k) {
        const int idx = nbr[(size_t)site * 27 + k];
        if (idx >= 0) {
            const float2 p = *(const float2*)(P + (size_t)k * pl + (size_t)idx * 2);
            s0 += p.x; s1 += p.y;
        }
    }
    float* row = ppn + (size_t)site * 6;
    const int* cr = coords + (size_t)site * 4;
    row[0] = (float)cr[0]; row[1] = (float)cr[1];
    row[2] = (float)cr[2]; row[3] = (float)cr[3];
    row[4] = s0; row[5] = s1;
}

// ---------------------------------------------------------------------------
// Pre-pass: f32 rows (optionally x att-mask) -> f16 split planes, plus a
// zero row at index N (gather target for missing neighbors / tail sites).
// ---------------------------------------------------------------------------
template<int TERMS>
__global__ __launch_bounds__(256)
void prepass(const float* __restrict__ f, const float* __restrict__ att,
             f16* __restrict__ dst, size_t plane, int C4, int N)
{
    const size_t i = (size_t)blockIdx.x * 256 + threadIdx.x;
    const size_t total = (size_t)(N + 1) * C4;
    if (i >= total) return;
    const int row = (int)(i / C4);
    float4 v = make_float4(0.f, 0.f, 0.f, 0.f);
    if (row < N) {
        v = *(const float4*)(f + i * 4);
        if (att != nullptr) {
            const float a = att[row];
            v.x *= a; v.y *= a; v.z *= a; v.w *= a;
        }
    }
    const float xs[4] = {v.x, v.y, v.z, v.w};
    f16x4 hi, lo;
#pragma unroll
    for (int j = 0; j < 4; ++j) {
        const f16 h = (f16)xs[j];
        hi[j] = h;
        lo[j] = (f16)((xs[j] - (float)h) * 4096.f);
    }
    *(f16x4*)(dst + i * 4) = hi;
    if constexpr (TERMS == 2)
        *(f16x4*)(dst + plane + i * 4) = lo;
}

// Pack fp32 W[27][C][CO_real] into 16x16 fragment chunks:
// chunk id = ((((k*CS + cs)*KK + kk)*NTB + nt)*TERMS + term), 512 f16 each.
__global__ __launch_bounds__(256)
void pack_w_f16(const float* __restrict__ W, f16* __restrict__ Wb,
                int C, int CO_real, int CS, int NTB, int TERMS)
{
    const int KK = C / 32;
    const int total = 27 * CS * KK * NTB * TERMS * 64;
    const int t = blockIdx.x * blockDim.x + threadIdx.x;
    if (t >= total) return;
    const int lane = t & 63;
    int cid = t >> 6;
    const int term = cid % TERMS; cid /= TERMS;
    const int nt   = cid % NTB;   cid /= NTB;
    const int kk   = cid % KK;    cid /= KK;
    const int cs   = cid % CS;
    const int k    = cid / CS;
    const int co   = (cs * NTB + nt) * 16 + (lane & 15);
#pragma unroll
    for (int j = 0; j < 8; ++j) {
        const int ci = kk * 32 + (lane >> 4) * 8 + j;
        const float x = (co < CO_real) ? W[((size_t)k * C + ci) * CO_real + co] : 0.f;
        const f16 h = (f16)x;
        Wb[(size_t)t * 8 + j] = (term == 0) ? h : (f16)((x - (float)h) * 4096.f);
    }
}

// Pack score weights [27][C][2] as a flat [C x 54->64] fragment set,
// chunk id = ((kk*4 + nt)*2 + term); flat col co = 2k + c.
__global__ __launch_bounds__(256)
void pack_ws_flat(const float* __restrict__ W, f16* __restrict__ Wb, int C)
{
    const int KK = C / 32;
    const int total = KK * 4 * 2 * 64;
    const int t = blockIdx.x * blockDim.x + threadIdx.x;
    if (t >= total) return;
    const int lane = t & 63;
    int cid = t >> 6;
    const int term = cid % 2;
    const int nt   = (cid >> 1) % 4;
    const int kk   = cid >> 3;
    const int co   = nt * 16 + (lane & 15);
#pragma unroll
    for (int j = 0; j < 8; ++j) {
        const int ci = kk * 32 + (lane >> 4) * 8 + j;
        const float x = (co < 54) ? W[((size_t)(co >> 1) * C + ci) * 2 + (co & 1)] : 0.f;
        const f16 h = (f16)x;
        Wb[(size_t)t * 8 + j] = (term == 0) ? h : (f16)((x - (float)h) * 4096.f);
    }
}

// Pack the fused head [27][32][{3|2|5}->10] directly into fragment chunks
// (chunk per k; single term).
__global__ __launch_bounds__(256)
void pack_wh_frag(const float* __restrict__ wp, const float* __restrict__ ws,
                  const float* __restrict__ wt, f16* __restrict__ Wb)
{
    const int t = blockIdx.x * blockDim.x + threadIdx.x;
    if (t >= 27 * 64) return;
    const int lane = t & 63;
    const int k    = t >> 6;
    const int co   = lane & 15;
#pragma unroll
    for (int j = 0; j < 8; ++j) {
        const int ci = (lane >> 4) * 8 + j;
        float x = 0.f;
        if (co < 3)       x = wp[((size_t)k * 32 + ci) * 3 + co];
        else if (co < 5)  x = ws[((size_t)k * 32 + ci) * 2 + (co - 3)];
        else if (co < 10) x = wt[((size_t)k * 32 + ci) * 5 + (co - 5)];
        Wb[(size_t)t * 8 + j] = (f16)x;
    }
}

__global__ __launch_bounds__(256)
void att_kernel(const float* __restrict__ ppn, const int* __restrict__ parent,
                float* __restrict__ att, int N)
{
    const int i = blockIdx.x * blockDim.x + threadIdx.x;
    if (i >= N) return;
    const int p = parent[i];
    const float s0 = ppn[(size_t)p * 6 + 4];
    const float s1 = ppn[(size_t)p * 6 + 5];
    const float m  = fmaxf(s0, s1);
    const float e0 = expf(s0 - m);
    const float e1 = expf(s1 - m);
    const float p1 = e1 / (e0 + e1);
    att[i] = (p1 > 0.8f) ? 1.f : 0.f;
}

extern "C" void kernel_launch(void* const* d_in, const int* in_sizes, int n_in,
                              void* d_out, int out_size, void* d_ws, size_t ws_size,
                              hipStream_t stream)
{
    const float* f1       = (const float*)d_in[0];
    const float* f2       = (const float*)d_in[1];
    const float* f3       = (const float*)d_in[2];
    const float* w1_conv  = (const float*)d_in[3];
    const float* w1_score = (const float*)d_in[4];
    const float* w2_conv  = (const float*)d_in[5];
    const float* w2_score = (const float*)d_in[6];
    const float* w3_conv  = (const float*)d_in[7];
    const float* w3_pix   = (const float*)d_in[8];
    const float* w3_score = (const float*)d_in[9];
    const float* w3_type  = (const float*)d_in[10];
    const int* coords1    = (const int*)d_in[11];
    const int* coords2    = (const int*)d_in[12];
    const int* nbr1       = (const int*)d_in[13];
    const int* nbr2       = (const int*)d_in[14];
    const int* nbr3       = (const int*)d_in[15];
    const int* parent12   = (const int*)d_in[16];
    const int* parent23   = (const int*)d_in[17];

    const int N1 = in_sizes[0] / 160;   // 20000
    const int N2 = in_sizes[1] / 96;    // 160000
    const int N3 = in_sizes[2] / 32;    // 320000

    // Output layout: points[N3,10] | ppn1[N1,6] | ppn2[N2,6] | att[N2] | att2[N3]
    float* points = (float*)d_out;
    float* ppn1   = points + (size_t)N3 * 10;
    float* ppn2   = ppn1 + (size_t)N1 * 6;
    float* attn   = ppn2 + (size_t)N2 * 6;
    float* attn2  = attn + (size_t)N2;

    // Workspace (all conv inputs have N+1 rows; row N = zeros).
    const size_t p1 = (size_t)(N1 + 1) * 160;
    const size_t p2 = (size_t)(N2 + 1) * 96;
    const size_t p3 = (size_t)(N3 + 1) * 32;
    f16* f1s  = (f16*)d_ws;           // 2*p1 = 12.8MB
    f16* xs   = f1s + 2 * p1;         // 2*p1
    f16* f2s  = xs + 2 * p1;          // 2*p2 = 61.4MB
    f16* ys   = f2s + 2 * p2;         // 2*p2
    float* P1 = (float*)f1s;          // 4.3MB  (dead after reduce1)
    int* nbr2m = (int*)f1s;           // 17.3MB <= 25.6MB (f1s+xs)
    f16* f3s  = f1s;                  // 20.5MB (after conv2)
    float* P2 = (float*)f2s;          // 34.6MB (dead after reduce2)
    f16* zs   = f2s;                  // 20.5MB
    int* nbr3m = (int*)((char*)f2s + ((p3 * 2 + 255) & ~(size_t)255));
    f16* Wb1  = ys + 2 * p2;                // 2700 chunks
    f16* Wb2  = Wb1 + (size_t)2700 * 512;   // 972
    f16* Wb3  = Wb2 + (size_t)972 * 512;    // 54
    f16* Wbh  = Wb3 + (size_t)54 * 512;     // 27
    f16* Wsf1 = Wbh + (size_t)27 * 512;     // 40 (score1 flat)
    f16* Wsf2 = Wsf1 + (size_t)40 * 512;    // 24 (score2 flat)

    // ---- weight packing ----
    pack_w_f16<<<(2700 * 64 + 255) / 256, 256, 0, stream>>>(w1_conv, Wb1, 160, 160, 2, 5, 2);
    pack_w_f16<<<(972 * 64 + 255) / 256, 256, 0, stream>>>(w2_conv, Wb2, 96, 96, 2, 3, 2);
    pack_w_f16<<<(54 * 64 + 255) / 256, 256, 0, stream>>>(w3_conv, Wb3, 32, 32, 1, 2, 1);
    pack_wh_frag<<<(27 * 64 + 255) / 256, 256, 0, stream>>>(w3_pix, w3_score, w3_type, Wbh);
    pack_ws_flat<<<(40 * 64 + 255) / 256, 256, 0, stream>>>(w1_score, Wsf1, 160);
    pack_ws_flat<<<(24 * 64 + 255) / 256, 256, 0, stream>>>(w2_score, Wsf2, 96);

    // ---- level 1 ----
    prepass<2><<<(int)(((size_t)(N1 + 1) * 40 + 255) / 256), 256, 0, stream>>>(
        f1, nullptr, f1s, p1, 40, N1);
    // conv1: C=160 NTB=5 CS=2 WCO=1 MROW=1, sbuf, WAVES=4 (R16-proven).
    conv_mfma<160, 5, 2, 1, 2, 4, 2, 2, 0, 1, 0><<<316 * 2, 256, 0, stream>>>(
        f1s, p1, nbr1, Wb1, xs, 160, 0, p1, 160, N1, N1 + 1, 316);
    pgemm_score<160><<<(N1 + 63) / 64, 256, 0, stream>>>(xs, p1, Wsf1, P1, N1);
    reduce_score<<<(N1 + 255) / 256, 256, 0, stream>>>(P1, nbr1, coords1, ppn1, N1);
    att_kernel<<<(N2 + 255) / 256, 256, 0, stream>>>(ppn1, parent12, attn, N2);

    // ---- level 2 ----
    remap_nbr<<<(int)(((size_t)N2 * 27 + 255) / 256), 256, 0, stream>>>(
        nbr2, attn, nbr2m, (size_t)N2 * 27);
    prepass<2><<<(int)(((size_t)(N2 + 1) * 24 + 255) / 256), 256, 0, stream>>>(
        f2, attn, f2s, p2, 24, N2);
    // conv2: R13 geometry + SKIPZ (wave skips ds_read+MFMA when its whole
    // A-tile is the zero row; exact). tiles=1250 -> pad 1252, nwg=2504.
    conv_mfma<96, 3, 2, 1, 2, 8, 1, 2, 0, 1, 1><<<1252 * 2, 512, 0, stream>>>(
        f2s, p2, nbr2m, Wb2, ys, 96, 0, p2, 96, N2, N2 + 1, 1252);
    pgemm_score<96><<<(N2 + 63) / 64, 256, 0, stream>>>(ys, p2, Wsf2, P2, N2);
    reduce_score<<<(N2 + 255) / 256, 256, 0, stream>>>(P2, nbr2, coords2, ppn2, N2);
    att_kernel<<<(N3 + 255) / 256, 256, 0, stream>>>(ppn2, parent23, attn2, N3);

    // ---- level 3 (points chain, single-term f16) ----
    remap_nbr<<<(int)(((size_t)N3 * 27 + 255) / 256), 256, 0, stream>>>(
        nbr3, attn2, nbr3m, (size_t)N3 * 27);
    prepass<1><<<(int)(((size_t)(N3 + 1) * 8 + 255) / 256), 256, 0, stream>>>(
        f3, attn2, f3s, 0, 8, N3);
    // conv3: whole-B, PIPEA, MROW=1 + SKIPZ (input masked by att2).
    conv_mfma<32, 2, 1, 1, 1, 8, 0, 1, 1, 1, 1><<<2504, 512, 0, stream>>>(
        f3s, 0, nbr3m, Wb3, zs, 32, 0, 0, 32, N3, N3 + 1, 2504);
    // head: whole-B, PIPEA, MROW=1. zs NOT masked -> nbr3, no skip.
    conv_mfma<32, 1, 1, 1, 1, 8, 0, 0, 1, 1, 0><<<2504, 512, 0, stream>>>(
        zs, 0, nbr3, Wbh, points, 10, 0, 0, 10, N3, N3, 2504);
}

// Round 18
// 484.338 us; speedup vs baseline: 1.4224x; 1.0388x over previous
//
#include <hip/hip_runtime.h>
#include <cstddef>

typedef _Float16 f16;
typedef f16 f16x4 __attribute__((ext_vector_type(4)));
typedef f16 f16x8 __attribute__((ext_vector_type(8)));
typedef float f32x4 __attribute__((ext_vector_type(4)));

// async global->LDS, 16B per lane. LDS dest = uniform base + lane*16 (HW);
// global src is per-lane.
__device__ inline void gld_lds16(const f16* g, f16* l) {
    __builtin_amdgcn_global_load_lds(
        (const __attribute__((address_space(1))) void*)g,
        (__attribute__((address_space(3))) void*)l, 16, 0, 0);
}

// ---------------------------------------------------------------------------
// 16x16x32 MFMA submanifold conv, A-direct / B-in-LDS.
//  - GEOMETRY (R5..R17 measured): conv2 = NTB=3 CS=2 MROW=1 WAVES=8 dbuf.
//    conv1 = sbuf WAVES=4. conv3/head = whole-B BMODE=0 MROW=1 grid 2504.
//  - MASK REMAP (R13) + SKIPZ (R17, -95us): nbr remapped so masked gathers
//    hit the zero row; a wave whose entire 16-row A-tile is the zero row
//    skips A-loads + ds_reads + MFMAs for that k (exact; barriers kept).
//  - TERMS=2: Markidis f16 split (hi + lo*2^12), 3 MFMAs/pair -> ~fp32
//    accuracy (mask-threshold chain). TERMS=1: plain f16 (points chain).
//  - Bijective XCD-chunk swizzle (nwg % 8 == 0).
// ---------------------------------------------------------------------------
template<int C, int NTB, int CS, int WCO, int TERMS, int WAVES, int BMODE,
         int OUTM, int PIPEA, int MROW, int SKIPZ>
__global__ __launch_bounds__(WAVES * 64)
void conv_mfma(const f16* __restrict__ fin, size_t in_plane,
               const int* __restrict__ nbr,
               const f16* __restrict__ Wb,
               void* __restrict__ outv, int ostride, int ooff, size_t out_plane,
               int CO_real, int N, int Nstore, int tilesPad)
{
    constexpr int KK   = C / 32;
    constexpr int KKL  = (TERMS == 2) ? KK : 1;
    constexpr int NTBT = WCO * NTB;
    constexpr int CH   = KK * NTBT * TERMS;
    constexpr int WROW = WAVES / WCO;
    constexpr int ROWS = WROW * MROW * 16;
    constexpr int BUFS = (BMODE == 0) ? 27 : ((BMODE == 1) ? 2 : 1);
    __shared__ f16 sB[BUFS * CH * 512];

    const int lane = threadIdx.x & 63;
    const int w    = threadIdx.x >> 6;
    const int wco  = w % WCO;
    const int wrow = w / WCO;
    int gid = blockIdx.x;
    { const int q = (tilesPad * CS) >> 3; gid = (gid & 7) * q + (gid >> 3); }
    const int tile = gid / CS;
    const int cs   = gid - tile * CS;
    const int n0   = tile * ROWS;
    const int NZ   = N;                          // zero row
    const int h8   = (lane >> 4) * 8;

    int  site[MROW];
    bool sv[MROW];
#pragma unroll
    for (int r = 0; r < MROW; ++r) {
        site[r] = n0 + (wrow * MROW + r) * 16 + (lane & 15);
        sv[r]   = site[r] < N;
    }

    auto nbrIdx = [&](int r, int k) -> int {
        int v = sv[r] ? nbr[(size_t)site[r] * 27 + k] : -1;
        return (v < 0) ? NZ : v;
    };

    // Wave-uniform: true iff every gathered row of this wave is the zero row.
    auto allNZ = [&](const int* ix) -> bool {
        if constexpr (!SKIPZ) return false;
        int m = 1;
#pragma unroll
        for (int r = 0; r < MROW; ++r) m &= (ix[r] == NZ);
        return __all(m);
    };

    auto stageK = [&](int k, int buf) {
        const f16* src = Wb + ((size_t)(k * CS + cs) * CH) * 512 + lane * 8;
        f16* dst = &sB[(size_t)buf * CH * 512];
#pragma unroll
        for (int c = w; c < CH; c += WAVES)
            gld_lds16(src + (size_t)c * 512, dst + (size_t)c * 512);
    };

    f32x4 acc[MROW * NTB], acc2[MROW * NTB];
#pragma unroll
    for (int i = 0; i < MROW * NTB; ++i) {
        acc[i]  = (f32x4){0.f, 0.f, 0.f, 0.f};
        acc2[i] = (f32x4){0.f, 0.f, 0.f, 0.f};
    }

    f16x8 va[MROW * KK], vl[MROW * KKL];
    f16x8 vaB[(BMODE == 0 && PIPEA) ? MROW * KK : 1];
    f16x8 vlB[(BMODE == 0 && PIPEA) ? MROW * KKL : 1];

    auto loadA = [&](int idx, f16x8* pva, f16x8* pvl) {
        const f16* arow = fin + (size_t)idx * C + h8;
#pragma unroll
        for (int kk = 0; kk < KK; ++kk) {
            pva[kk] = *(const f16x8*)(arow + kk * 32);
            if constexpr (TERMS == 2)
                pvl[kk] = *(const f16x8*)(arow + in_plane + kk * 32);
        }
    };

    auto mfmaPhase = [&](const f16x8* pva, const f16x8* pvl, int kbuf) {
        const f16* sBc = &sB[(size_t)kbuf * CH * 512] + lane * 8;
#pragma unroll
        for (int kk = 0; kk < KK; ++kk) {
#pragma unroll
            for (int nt = 0; nt < NTB; ++nt) {
                const f16* bp = sBc + (size_t)((kk * NTBT + wco * NTB + nt) * TERMS) * 512;
                const f16x8 bh = *(const f16x8*)bp;
                if constexpr (TERMS == 2) {
                    const f16x8 bl = *(const f16x8*)(bp + 512);
#pragma unroll
                    for (int r = 0; r < MROW; ++r) {
                        acc[r * NTB + nt]  = __builtin_amdgcn_mfma_f32_16x16x32_f16(
                            pva[r * KK + kk], bh, acc[r * NTB + nt], 0, 0, 0);
                        acc2[r * NTB + nt] = __builtin_amdgcn_mfma_f32_16x16x32_f16(
                            pva[r * KK + kk], bl, acc2[r * NTB + nt], 0, 0, 0);
                        acc2[r * NTB + nt] = __builtin_amdgcn_mfma_f32_16x16x32_f16(
                            pvl[r * KK + kk], bh, acc2[r * NTB + nt], 0, 0, 0);
                    }
                } else {
#pragma unroll
                    for (int r = 0; r < MROW; ++r)
                        acc[r * NTB + nt] = __builtin_amdgcn_mfma_f32_16x16x32_f16(
                            pva[r * KK + kk], bh, acc[r * NTB + nt], 0, 0, 0);
                }
            }
        }
    };

    if constexpr (BMODE == 1) {
        // ---- per-k dbuf; 1 barrier/k; A(k+1) issued pre-drain; SKIPZ ----
        int idxN[MROW];
        bool skipC, skipN;
        {
            int idx0[MROW];
#pragma unroll
            for (int r = 0; r < MROW; ++r) idx0[r] = nbrIdx(r, 0);
            skipC = allNZ(idx0);
            if (!skipC)
#pragma unroll
                for (int r = 0; r < MROW; ++r)
                    loadA(idx0[r], &va[r * KK], &vl[r * KKL]);
        }
        stageK(0, 0);
#pragma unroll
        for (int r = 0; r < MROW; ++r) idxN[r] = nbrIdx(r, 1);
        skipN = allNZ(idxN);
        __syncthreads();

        for (int k = 0; k < 27; ++k) {
            if (k + 1 < 27) stageK(k + 1, (k + 1) & 1);
            if (!skipC) mfmaPhase(va, vl, k & 1);
            if (k + 1 < 27) {
                if (!skipN)
#pragma unroll
                    for (int r = 0; r < MROW; ++r)
                        loadA(idxN[r], &va[r * KK], &vl[r * KKL]);
                skipC = skipN;
#pragma unroll
                for (int r = 0; r < MROW; ++r)
                    idxN[r] = (k + 2 < 27) ? nbrIdx(r, k + 2) : NZ;
                skipN = allNZ(idxN);
                __syncthreads();
            }
        }
    } else if constexpr (BMODE == 2) {
        // ---- per-k single buffer; 2 barriers/k (covered by co-res blocks) ----
        int idxN[MROW];
#pragma unroll
        for (int r = 0; r < MROW; ++r)
            loadA(nbrIdx(r, 0), &va[r * KK], &vl[r * KKL]);
#pragma unroll
        for (int r = 0; r < MROW; ++r) idxN[r] = nbrIdx(r, 1);

        for (int k = 0; k < 27; ++k) {
            stageK(k, 0);
            __syncthreads();
            mfmaPhase(va, vl, 0);
            if (k + 1 < 27) {
#pragma unroll
                for (int r = 0; r < MROW; ++r)
                    loadA(idxN[r], &va[r * KK], &vl[r * KKL]);
#pragma unroll
                for (int r = 0; r < MROW; ++r)
                    idxN[r] = (k + 2 < 27) ? nbrIdx(r, k + 2) : NZ;
                __syncthreads();
            }
        }
    } else {
        // ---- whole-B resident, no k-loop barriers; PIPEA A reg-dbuf; SKIPZ ----
#pragma unroll
        for (int c = w; c < 27 * CH; c += WAVES)
            gld_lds16(Wb + (size_t)c * 512 + lane * 8, &sB[(size_t)c * 512]);
        int idxN[MROW];
        bool skipC, skipN;
        {
            int idx0[MROW];
#pragma unroll
            for (int r = 0; r < MROW; ++r) idx0[r] = nbrIdx(r, 0);
            skipC = allNZ(idx0);
            if (!skipC)
#pragma unroll
                for (int r = 0; r < MROW; ++r)
                    loadA(idx0[r], &va[r * KK], &vl[r * KKL]);
        }
#pragma unroll
        for (int r = 0; r < MROW; ++r) idxN[r] = nbrIdx(r, 1);
        skipN = allNZ(idxN);
        __syncthreads();

        if constexpr (PIPEA) {
            auto body = [&](int k, f16x8* vac, f16x8* vlc, f16x8* van, f16x8* vln) {
                if (k >= 27) return;
                bool nextC = skipN;
                if (k + 1 < 27) {
                    if (!skipN)
#pragma unroll
                        for (int r = 0; r < MROW; ++r)
                            loadA(idxN[r], &van[r * KK], &vln[r * KKL]);
#pragma unroll
                    for (int r = 0; r < MROW; ++r)
                        idxN[r] = (k + 2 < 27) ? nbrIdx(r, k + 2) : NZ;
                    skipN = allNZ(idxN);
                }
                if (!skipC) mfmaPhase(vac, vlc, k);
                skipC = nextC;
            };
            for (int k2 = 0; k2 < 27; k2 += 2) {
                body(k2, va, vl, vaB, vlB);
                body(k2 + 1, vaB, vlB, va, vl);
            }
        } else {
            for (int k = 0; k < 27; ++k) {
                if (!skipC) mfmaPhase(va, vl, k);
                if (k + 1 < 27) {
                    if (!skipN)
#pragma unroll
                        for (int r = 0; r < MROW; ++r)
                            loadA(idxN[r], &va[r * KK], &vl[r * KKL]);
                    skipC = skipN;
#pragma unroll
                    for (int r = 0; r < MROW; ++r)
                        idxN[r] = (k + 2 < 27) ? nbrIdx(r, k + 2) : NZ;
                    skipN = allNZ(idxN);
                }
            }
        }
    }

    // ---- epilogue: D col=lane&15, row=(lane>>4)*4+j ----
    const int colg = lane & 15;
    const int rg   = lane >> 4;
#pragma unroll
    for (int r = 0; r < MROW; ++r) {
#pragma unroll
        for (int nt = 0; nt < NTB; ++nt) {
#pragma unroll
            for (int j = 0; j < 4; ++j) {
                float v = acc[r * NTB + nt][j];
                if constexpr (TERMS == 2) v += acc2[r * NTB + nt][j] * (1.f / 4096.f);
                const int n  = n0 + (wrow * MROW + r) * 16 + rg * 4 + j;
                const int co = ((cs * WCO + wco) * NTB + nt) * 16 + colg;
                if (n < Nstore && co < CO_real) {
                    if constexpr (OUTM == 0) {
                        ((float*)outv)[(size_t)n * ostride + ooff + co] = v;
                    } else if constexpr (OUTM == 1) {
                        ((f16*)outv)[(size_t)n * ostride + co] = (f16)v;
                    } else {
                        f16* o = (f16*)outv;
                        const f16 h = (f16)v;
                        o[(size_t)n * ostride + co] = h;
                        o[out_plane + (size_t)n * ostride + co] = (f16)((v - (float)h) * 4096.f);
                    }
                }
            }
        }
    }
}

// nbrm[i] = nbr[i] if that neighbor survives the attention mask, else -1.
__global__ __launch_bounds__(256)
void remap_nbr(const int* __restrict__ nbr, const float* __restrict__ att,
               int* __restrict__ nbrm, size_t total)
{
    const size_t i = (size_t)blockIdx.x * 256 + threadIdx.x;
    if (i >= total) return;
    const int j = nbr[i];
    nbrm[i] = (j >= 0 && att[j] > 0.5f) ? j : -1;
}

// zmask[site] = 1 iff site has any surviving (non-remapped) neighbor, i.e.
// its conv3 output row z[site] is NOT identically zero.
__global__ __launch_bounds__(256)
void zmask_kernel(const int* __restrict__ nbrm, int* __restrict__ zm, int N)
{
    const int site = blockIdx.x * 256 + threadIdx.x;
    if (site >= N) return;
    int any = 0;
#pragma unroll
    for (int k = 0; k < 27; ++k)
        any |= (nbrm[(size_t)site * 27 + k] >= 0);
    zm[site] = any;
}

// nbrz[i] = nbr[i] if z[nbr[i]] is nonzero (per zmask), else -1.
__global__ __launch_bounds__(256)
void remap_nbr_zm(const int* __restrict__ nbr, const int* __restrict__ zm,
                  int* __restrict__ nbrz, size_t total)
{
    const size_t i = (size_t)blockIdx.x * 256 + threadIdx.x;
    if (i >= total) return;
    const int j = nbr[i];
    nbrz[i] = (j >= 0 && zm[j]) ? j : -1;
}

// ---------------------------------------------------------------------------
// P-factorized score: P[k][R][c] = f[R] @ Ws[k][:,c] as ONE dense GEMM
// f[N x C] @ Wflat[C x 54->64] (no gather). P is f32 [27][N][2].
// ---------------------------------------------------------------------------
template<int C>
__global__ __launch_bounds__(256)
void pgemm_score(const f16* __restrict__ fin, size_t plane,
                 const f16* __restrict__ Wb,   // (C/32)*4*2 chunks
                 float* __restrict__ P, int N)
{
    constexpr int KK = C / 32;
    constexpr int CH = KK * 4 * 2;
    __shared__ f16 sB[CH * 512];

    const int tid  = threadIdx.x;
    const int lane = tid & 63;
    const int w    = tid >> 6;

    const int n0 = blockIdx.x * 64;
    int site = n0 + w * 16 + (lane & 15);
    if (site > N) site = N;                 // zero row for tails
    const int h8 = (lane >> 4) * 8;

    f16x8 va[KK], vl[KK];
    const f16* arow = fin + (size_t)site * C + h8;
#pragma unroll
    for (int kk = 0; kk < KK; ++kk) {
        va[kk] = *(const f16x8*)(arow + kk * 32);
        vl[kk] = *(const f16x8*)(arow + plane + kk * 32);
    }
    for (int c = w; c < CH; c += 4)
        gld_lds16(Wb + (size_t)c * 512 + lane * 8, &sB[(size_t)c * 512]);

    f32x4 acc[4], acc2[4];
#pragma unroll
    for (int nt = 0; nt < 4; ++nt) {
        acc[nt]  = (f32x4){0.f, 0.f, 0.f, 0.f};
        acc2[nt] = (f32x4){0.f, 0.f, 0.f, 0.f};
    }
    __syncthreads();

#pragma unroll
    for (int kk = 0; kk < KK; ++kk) {
#pragma unroll
        for (int nt = 0; nt < 4; ++nt) {
            const f16* bp = &sB[(size_t)((kk * 4 + nt) * 2) * 512] + lane * 8;
            const f16x8 bh = *(const f16x8*)bp;
            const f16x8 bl = *(const f16x8*)(bp + 512);
            acc[nt]  = __builtin_amdgcn_mfma_f32_16x16x32_f16(va[kk], bh, acc[nt], 0, 0, 0);
            acc2[nt] = __builtin_amdgcn_mfma_f32_16x16x32_f16(va[kk], bl, acc2[nt], 0, 0, 0);
            acc2[nt] = __builtin_amdgcn_mfma_f32_16x16x32_f16(vl[kk], bh, acc2[nt], 0, 0, 0);
        }
    }

    const int colg = lane & 15;
    const int rg   = lane >> 4;
#pragma unroll
    for (int nt = 0; nt < 4; ++nt) {
#pragma unroll
        for (int j = 0; j < 4; ++j) {
            const float r = acc[nt][j] + acc2[nt][j] * (1.f / 4096.f);
            const int n  = n0 + w * 16 + rg * 4 + j;
            const int co = nt * 16 + colg;
            if (n < N && co < 54)
                P[(size_t)(co >> 1) * N * 2 + (size_t)n * 2 + (co & 1)] = r;
        }
    }
}

// score(S) = sum_k P[k][nbr(S,k)]  (f32, k-ordered like the reference);
// also fills the coords columns of ppn.
__global__ __launch_bounds__(256)
void reduce_score(const float* __restrict__ P, const int* __restrict__ nbr,
                  const int* __restrict__ coords, float* __restrict__ ppn, int N)
{
    const int site = blockIdx.x * 256 + threadIdx.x;
    if (site >= N) return;
    float s0 = 0.f, s1 = 0.f;
    const size_t pl = (size_t)N * 2;
#pragma unroll
    for (int k = 0; k < 27; ++k) {
        const int idx = nbr[(size_t)site * 27 + k];
        if (idx >= 0) {
            const float2 p = *(const float2*)(P + (size_t)k * pl + (size_t)idx * 2);
            s0 += p.x; s1 += p.y;
        }
    }
    float* row = ppn + (size_t)site * 6;
    const int* cr = coords + (size_t)site * 4;
    row[0] = (float)cr[0]; row[1] = (float)cr[1];
    row[2] = (float)cr[2]; row[3] = (float)cr[3];
    row[4] = s0; row[5] = s1;
}

// ---------------------------------------------------------------------------
// Pre-pass: f32 rows (optionally x att-mask) -> f16 split planes, plus a
// zero row at index N. SPARSE=1 (R18): rows with att==0 are skipped entirely
// (no read, no write) -- they are unreachable (all gathers of masked rows
// are redirected to the zero row by the nbr remap).
// ---------------------------------------------------------------------------
template<int TERMS, int SPARSE>
__global__ __launch_bounds__(256)
void prepass(const float* __restrict__ f, const float* __restrict__ att,
             f16* __restrict__ dst, size_t plane, int C4, int N)
{
    const size_t i = (size_t)blockIdx.x * 256 + threadIdx.x;
    const size_t total = (size_t)(N + 1) * C4;
    if (i >= total) return;
    const int row = (int)(i / C4);
    float4 v = make_float4(0.f, 0.f, 0.f, 0.f);
    if (row < N) {
        float a = 1.f;
        if (att != nullptr) {
            a = att[row];
            if (SPARSE && a == 0.f) return;   // row unreachable: skip entirely
        }
        v = *(const float4*)(f + i * 4);
        v.x *= a; v.y *= a; v.z *= a; v.w *= a;
    }
    const float xs[4] = {v.x, v.y, v.z, v.w};
    f16x4 hi, lo;
#pragma unroll
    for (int j = 0; j < 4; ++j) {
        const f16 h = (f16)xs[j];
        hi[j] = h;
        lo[j] = (f16)((xs[j] - (float)h) * 4096.f);
    }
    *(f16x4*)(dst + i * 4) = hi;
    if constexpr (TERMS == 2)
        *(f16x4*)(dst + plane + i * 4) = lo;
}

// Pack fp32 W[27][C][CO_real] into 16x16 fragment chunks:
// chunk id = ((((k*CS + cs)*KK + kk)*NTB + nt)*TERMS + term), 512 f16 each.
__global__ __launch_bounds__(256)
void pack_w_f16(const float* __restrict__ W, f16* __restrict__ Wb,
                int C, int CO_real, int CS, int NTB, int TERMS)
{
    const int KK = C / 32;
    const int total = 27 * CS * KK * NTB * TERMS * 64;
    const int t = blockIdx.x * blockDim.x + threadIdx.x;
    if (t >= total) return;
    const int lane = t & 63;
    int cid = t >> 6;
    const int term = cid % TERMS; cid /= TERMS;
    const int nt   = cid % NTB;   cid /= NTB;
    const int kk   = cid % KK;    cid /= KK;
    const int cs   = cid % CS;
    const int k    = cid / CS;
    const int co   = (cs * NTB + nt) * 16 + (lane & 15);
#pragma unroll
    for (int j = 0; j < 8; ++j) {
        const int ci = kk * 32 + (lane >> 4) * 8 + j;
        const float x = (co < CO_real) ? W[((size_t)k * C + ci) * CO_real + co] : 0.f;
        const f16 h = (f16)x;
        Wb[(size_t)t * 8 + j] = (term == 0) ? h : (f16)((x - (float)h) * 4096.f);
    }
}

// Pack score weights [27][C][2] as a flat [C x 54->64] fragment set,
// chunk id = ((kk*4 + nt)*2 + term); flat col co = 2k + c.
__global__ __launch_bounds__(256)
void pack_ws_flat(const float* __restrict__ W, f16* __restrict__ Wb, int C)
{
    const int KK = C / 32;
    const int total = KK * 4 * 2 * 64;
    const int t = blockIdx.x * blockDim.x + threadIdx.x;
    if (t >= total) return;
    const int lane = t & 63;
    int cid = t >> 6;
    const int term = cid % 2;
    const int nt   = (cid >> 1) % 4;
    const int kk   = cid >> 3;
    const int co   = nt * 16 + (lane & 15);
#pragma unroll
    for (int j = 0; j < 8; ++j) {
        const int ci = kk * 32 + (lane >> 4) * 8 + j;
        const float x = (co < 54) ? W[((size_t)(co >> 1) * C + ci) * 2 + (co & 1)] : 0.f;
        const f16 h = (f16)x;
        Wb[(size_t)t * 8 + j] = (term == 0) ? h : (f16)((x - (float)h) * 4096.f);
    }
}

// Pack the fused head [27][32][{3|2|5}->10] directly into fragment chunks
// (chunk per k; single term).
__global__ __launch_bounds__(256)
void pack_wh_frag(const float* __restrict__ wp, const float* __restrict__ ws,
                  const float* __restrict__ wt, f16* __restrict__ Wb)
{
    const int t = blockIdx.x * blockDim.x + threadIdx.x;
    if (t >= 27 * 64) return;
    const int lane = t & 63;
    const int k    = t >> 6;
    const int co   = lane & 15;
#pragma unroll
    for (int j = 0; j < 8; ++j) {
        const int ci = (lane >> 4) * 8 + j;
        float x = 0.f;
        if (co < 3)       x = wp[((size_t)k * 32 + ci) * 3 + co];
        else if (co < 5)  x = ws[((size_t)k * 32 + ci) * 2 + (co - 3)];
        else if (co < 10) x = wt[((size_t)k * 32 + ci) * 5 + (co - 5)];
        Wb[(size_t)t * 8 + j] = (f16)x;
    }
}

__global__ __launch_bounds__(256)
void att_kernel(const float* __restrict__ ppn, const int* __restrict__ parent,
                float* __restrict__ att, int N)
{
    const int i = blockIdx.x * blockDim.x + threadIdx.x;
    if (i >= N) return;
    const int p = parent[i];
    const float s0 = ppn[(size_t)p * 6 + 4];
    const float s1 = ppn[(size_t)p * 6 + 5];
    const float m  = fmaxf(s0, s1);
    const float e0 = expf(s0 - m);
    const float e1 = expf(s1 - m);
    const float p1 = e1 / (e0 + e1);
    att[i] = (p1 > 0.8f) ? 1.f : 0.f;
}

extern "C" void kernel_launch(void* const* d_in, const int* in_sizes, int n_in,
                              void* d_out, int out_size, void* d_ws, size_t ws_size,
                              hipStream_t stream)
{
    const float* f1       = (const float*)d_in[0];
    const float* f2       = (const float*)d_in[1];
    const float* f3       = (const float*)d_in[2];
    const float* w1_conv  = (const float*)d_in[3];
    const float* w1_score = (const float*)d_in[4];
    const float* w2_conv  = (const float*)d_in[5];
    const float* w2_score = (const float*)d_in[6];
    const float* w3_conv  = (const float*)d_in[7];
    const float* w3_pix   = (const float*)d_in[8];
    const float* w3_score = (const float*)d_in[9];
    const float* w3_type  = (const float*)d_in[10];
    const int* coords1    = (const int*)d_in[11];
    const int* coords2    = (const int*)d_in[12];
    const int* nbr1       = (const int*)d_in[13];
    const int* nbr2       = (const int*)d_in[14];
    const int* nbr3       = (const int*)d_in[15];
    const int* parent12   = (const int*)d_in[16];
    const int* parent23   = (const int*)d_in[17];

    const int N1 = in_sizes[0] / 160;   // 20000
    const int N2 = in_sizes[1] / 96;    // 160000
    const int N3 = in_sizes[2] / 32;    // 320000

    // Output layout: points[N3,10] | ppn1[N1,6] | ppn2[N2,6] | att[N2] | att2[N3]
    float* points = (float*)d_out;
    float* ppn1   = points + (size_t)N3 * 10;
    float* ppn2   = ppn1 + (size_t)N1 * 6;
    float* attn   = ppn2 + (size_t)N2 * 6;
    float* attn2  = attn + (size_t)N2;

    // Workspace (all conv inputs have N+1 rows; row N = zeros).
    const size_t p1 = (size_t)(N1 + 1) * 160;
    const size_t p2 = (size_t)(N2 + 1) * 96;
    const size_t p3 = (size_t)(N3 + 1) * 32;
    f16* f1s  = (f16*)d_ws;           // 2*p1 = 12.8MB
    f16* xs   = f1s + 2 * p1;         // 2*p1
    f16* f2s  = xs + 2 * p1;          // 2*p2 = 61.4MB
    f16* ys   = f2s + 2 * p2;         // 2*p2 (dead after pgemm2)
    float* P1 = (float*)f1s;          // 4.3MB  (dead after reduce1)
    int* nbr2m = (int*)f1s;           // 17.3MB <= 25.6MB (f1s+xs)
    f16* f3s  = f1s;                  // 20.5MB (after conv2)
    float* P2 = (float*)f2s;          // 34.6MB (dead after reduce2)
    f16* zs   = f2s;                  // 20.5MB
    int* nbr3m = (int*)((char*)f2s + ((p3 * 2 + 255) & ~(size_t)255));
                                      // 34.6MB, ends 55.1 <= 61.4MB
    int* zmask = (int*)ys;            // 1.28MB (ys dead after pgemm2)
    int* nbr3z = zmask + ((N3 + 64) & ~63);  // 34.6MB, ends ~36MB <= 61.4MB
    f16* Wb1  = ys + 2 * p2;                // 2700 chunks
    f16* Wb2  = Wb1 + (size_t)2700 * 512;   // 972
    f16* Wb3  = Wb2 + (size_t)972 * 512;    // 54
    f16* Wbh  = Wb3 + (size_t)54 * 512;     // 27
    f16* Wsf1 = Wbh + (size_t)27 * 512;     // 40 (score1 flat)
    f16* Wsf2 = Wsf1 + (size_t)40 * 512;    // 24 (score2 flat)

    // ---- weight packing ----
    pack_w_f16<<<(2700 * 64 + 255) / 256, 256, 0, stream>>>(w1_conv, Wb1, 160, 160, 2, 5, 2);
    pack_w_f16<<<(972 * 64 + 255) / 256, 256, 0, stream>>>(w2_conv, Wb2, 96, 96, 2, 3, 2);
    pack_w_f16<<<(54 * 64 + 255) / 256, 256, 0, stream>>>(w3_conv, Wb3, 32, 32, 1, 2, 1);
    pack_wh_frag<<<(27 * 64 + 255) / 256, 256, 0, stream>>>(w3_pix, w3_score, w3_type, Wbh);
    pack_ws_flat<<<(40 * 64 + 255) / 256, 256, 0, stream>>>(w1_score, Wsf1, 160);
    pack_ws_flat<<<(24 * 64 + 255) / 256, 256, 0, stream>>>(w2_score, Wsf2, 96);

    // ---- level 1 ----
    prepass<2, 0><<<(int)(((size_t)(N1 + 1) * 40 + 255) / 256), 256, 0, stream>>>(
        f1, nullptr, f1s, p1, 40, N1);
    // conv1: C=160 NTB=5 CS=2 WCO=1 MROW=1, sbuf, WAVES=4 (R16-proven).
    conv_mfma<160, 5, 2, 1, 2, 4, 2, 2, 0, 1, 0><<<316 * 2, 256, 0, stream>>>(
        f1s, p1, nbr1, Wb1, xs, 160, 0, p1, 160, N1, N1 + 1, 316);
    pgemm_score<160><<<(N1 + 63) / 64, 256, 0, stream>>>(xs, p1, Wsf1, P1, N1);
    reduce_score<<<(N1 + 255) / 256, 256, 0, stream>>>(P1, nbr1, coords1, ppn1, N1);
    att_kernel<<<(N2 + 255) / 256, 256, 0, stream>>>(ppn1, parent12, attn, N2);

    // ---- level 2 ----
    remap_nbr<<<(int)(((size_t)N2 * 27 + 255) / 256), 256, 0, stream>>>(
        nbr2, attn, nbr2m, (size_t)N2 * 27);
    // SPARSE prepass: masked f2s rows are unreachable (nbr2m) -> skipped.
    prepass<2, 1><<<(int)(((size_t)(N2 + 1) * 24 + 255) / 256), 256, 0, stream>>>(
        f2, attn, f2s, p2, 24, N2);
    // conv2: R13 geometry + SKIPZ. tiles=1250 -> pad 1252, nwg=2504.
    conv_mfma<96, 3, 2, 1, 2, 8, 1, 2, 0, 1, 1><<<1252 * 2, 512, 0, stream>>>(
        f2s, p2, nbr2m, Wb2, ys, 96, 0, p2, 96, N2, N2 + 1, 1252);
    pgemm_score<96><<<(N2 + 63) / 64, 256, 0, stream>>>(ys, p2, Wsf2, P2, N2);
    reduce_score<<<(N2 + 255) / 256, 256, 0, stream>>>(P2, nbr2, coords2, ppn2, N2);
    att_kernel<<<(N3 + 255) / 256, 256, 0, stream>>>(ppn2, parent23, attn2, N3);

    // ---- level 3 (points chain, single-term f16) ----
    remap_nbr<<<(int)(((size_t)N3 * 27 + 255) / 256), 256, 0, stream>>>(
        nbr3, attn2, nbr3m, (size_t)N3 * 27);
    // zmask: z[site] == 0 exactly iff no surviving neighbor (nbr3m all -1).
    zmask_kernel<<<(N3 + 255) / 256, 256, 0, stream>>>(nbr3m, zmask, N3);
    // nbr3z: head's gathers of zero z-rows redirected -> enables SKIPZ.
    remap_nbr_zm<<<(int)(((size_t)N3 * 27 + 255) / 256), 256, 0, stream>>>(
        nbr3, zmask, nbr3z, (size_t)N3 * 27);
    // SPARSE prepass: masked f3s rows are unreachable (nbr3m) -> skipped.
    prepass<1, 1><<<(int)(((size_t)(N3 + 1) * 8 + 255) / 256), 256, 0, stream>>>(
        f3, attn2, f3s, 0, 8, N3);
    // conv3: whole-B, PIPEA, MROW=1 + SKIPZ (input masked by att2).
    conv_mfma<32, 2, 1, 1, 1, 8, 0, 1, 1, 1, 1><<<2504, 512, 0, stream>>>(
        f3s, 0, nbr3m, Wb3, zs, 32, 0, 0, 32, N3, N3 + 1, 2504);
    // head: whole-B, PIPEA, MROW=1 + SKIPZ via z-sparsity (nbr3z).
    conv_mfma<32, 1, 1, 1, 1, 8, 0, 0, 1, 1, 1><<<2504, 512, 0, stream>>>(
        zs, 0, nbr3z, Wbh, points, 10, 0, 0, 10, N3, N3, 2504);
}